// Round 2
// baseline (1892.014 us; speedup 1.0000x reference)
//
#include <hip/hip_runtime.h>
#include <math.h>

#define NN 50000
#define NE 800000
#define FD 128
#define EDD 32
#define NG 64
#define NA 16
#define EPSV 1e-5f
#define NCH 196            // ceil(NN/256) chunks for the scan

__device__ __forceinline__ float sigf(float v) { return 1.0f / (1.0f + __expf(-v)); }

// ============ counting sort of edges by dst (CSR build) ====================
__global__ __launch_bounds__(256) void count_kernel(const int* __restrict__ ei,
                                                    int* __restrict__ off)
{
    const int e = blockIdx.x * 256 + threadIdx.x;   // grid covers NE exactly
    atomicAdd(&off[ei[NE + e]], 1);
}

__global__ __launch_bounds__(256) void scan1_kernel(const int* __restrict__ off,
                                                    int* __restrict__ chunk)
{
    __shared__ int red[256];
    const int i = blockIdx.x * 256 + threadIdx.x;
    red[threadIdx.x] = (i < NN) ? off[i] : 0;
    __syncthreads();
    for (int o = 128; o > 0; o >>= 1) {
        if (threadIdx.x < o) red[threadIdx.x] += red[threadIdx.x + o];
        __syncthreads();
    }
    if (threadIdx.x == 0) chunk[blockIdx.x] = red[0];
}

__global__ __launch_bounds__(256) void scan2_kernel(int* __restrict__ chunk)
{
    __shared__ int sh[256];
    const int t = threadIdx.x;
    const int v = (t < NCH) ? chunk[t] : 0;
    sh[t] = v;
    __syncthreads();
    for (int o = 1; o < 256; o <<= 1) {
        int x = (t >= o) ? sh[t - o] : 0;
        __syncthreads();
        sh[t] += x;
        __syncthreads();
    }
    if (t < NCH) chunk[t] = sh[t] - v;   // exclusive
}

__global__ __launch_bounds__(256) void scan3_kernel(int* __restrict__ off,
                                                    int* __restrict__ cur,
                                                    const int* __restrict__ chunk)
{
    __shared__ int sh[256];
    const int t = threadIdx.x;
    const int i = blockIdx.x * 256 + t;
    const int v = (i < NN) ? off[i] : 0;
    sh[t] = v;
    __syncthreads();
    for (int o = 1; o < 256; o <<= 1) {
        int x = (t >= o) ? sh[t - o] : 0;
        __syncthreads();
        sh[t] += x;
        __syncthreads();
    }
    const int ex = sh[t] - v + chunk[blockIdx.x];
    if (i < NN) { off[i] = ex; cur[i] = ex; }
    if (i == 0) off[NN] = NE;
}

__global__ __launch_bounds__(256) void scatter_kernel(const int* __restrict__ ei,
                                                      int* __restrict__ cur,
                                                      int2* __restrict__ perm)
{
    const int e = blockIdx.x * 256 + threadIdx.x;
    const int src = ei[e];
    const int dst = ei[NE + e];
    const int pos = atomicAdd(&cur[dst], 1);
    perm[pos] = make_int2(src, e);
}

// ============ gather-style edge stage ======================================
// xpa[n] = tr(x[n]) + sum_{e: dst=n} relu(tr(x[src_e]) + ea_e @ We^T + be)
// TR=false: tr=identity (stage 1). TR=true: tr(v)=relu(bn(v)) via fused A,B.
// Block = 256 threads = 2 nodes x 128 channels. We row held in registers,
// edge_attr read as wave-uniform float4 broadcasts. No atomics anywhere.
template<bool TR>
__global__ __launch_bounds__(256) void edge_agg_kernel(
    const float* __restrict__ xin, const float* __restrict__ cs,
    const float* __restrict__ cq, const float* __restrict__ ga,
    const float* __restrict__ bb, const float* __restrict__ eattr,
    const int* __restrict__ off, const int2* __restrict__ perm,
    const float* __restrict__ We, const float* __restrict__ be,
    float* __restrict__ xpa)
{
    const int t = threadIdx.x;
    const int c = t & 127;
    const int g = t >> 7;
    float w[32];
    {
        const float4* wv = (const float4*)(We + c * EDD);
#pragma unroll
        for (int i = 0; i < 8; ++i) {
            float4 v = wv[i];
            w[4 * i + 0] = v.x; w[4 * i + 1] = v.y;
            w[4 * i + 2] = v.z; w[4 * i + 3] = v.w;
        }
    }
    const float bec = be[c];
    float A = 1.0f, B = 0.0f;
    if (TR) {
        const float invN = 1.0f / (float)NN;
        const float m = cs[c] * invN;
        const float iv = rsqrtf(cq[c] * invN - m * m + EPSV);
        A = iv * ga[c];
        B = bb[c] - m * A;
    }
    const int node = blockIdx.x * 2 + g;
    const int lo = off[node], hi = off[node + 1];
    const float v0 = xin[(long)node * FD + c];
    float acc = TR ? fmaxf(fmaf(v0, A, B), 0.0f) : v0;
    for (int i = lo; i < hi; ++i) {
        const int2 se = perm[i];
        const float4* ev = (const float4*)(eattr + (long)se.y * EDD);
        float m = bec;
#pragma unroll
        for (int k = 0; k < 8; ++k) {
            const float4 v = ev[k];
            m = fmaf(v.x, w[4 * k + 0], m);
            m = fmaf(v.y, w[4 * k + 1], m);
            m = fmaf(v.z, w[4 * k + 2], m);
            m = fmaf(v.w, w[4 * k + 3], m);
        }
        float xs = xin[(long)se.x * FD + c];
        if (TR) xs = fmaxf(fmaf(xs, A, B), 0.0f);
        acc += fmaxf(m + xs, 0.0f);
    }
    xpa[(long)node * FD + c] = acc;
}

// ============ node GEMM: hpre = xpa @ W^T + b, fused BN column stats =======
__global__ __launch_bounds__(256) void node_kernel(
    const float* __restrict__ xpa, const float* __restrict__ W,
    const float* __restrict__ b, float* __restrict__ hpre,
    float* __restrict__ colsum, float* __restrict__ colsq)
{
    __shared__ float rowJ[8 * 132];
    __shared__ float red[256];
    const int t = threadIdx.x;
    const int c = t & 127;
    const int half = t >> 7;
    const int js = t & 7;
    const int kk = t >> 3;
    const float bc = b[c];
    const float4* wp = (const float4*)(W + c * FD);
    float s1 = 0.0f, s2 = 0.0f;
    const int stride = gridDim.x * 8;
    const int iters = (NN + stride - 1) / stride;
    for (int it = 0; it < iters; ++it) {
        const int r0 = (blockIdx.x + it * gridDim.x) * 8;
        __syncthreads();
        {
            const int r = r0 + js;
            float4 v = make_float4(0.f, 0.f, 0.f, 0.f);
            if (r < NN) v = *(const float4*)(xpa + (long)r * FD + kk * 4);
            *(float4*)(&rowJ[js * 132 + kk * 4]) = v;
        }
        __syncthreads();
        float a0 = 0.f, a1 = 0.f, a2 = 0.f, a3 = 0.f;
        const int jb = half * 4;
#pragma unroll 8
        for (int k4 = 0; k4 < 32; ++k4) {
            const float4 w4 = wp[k4];
            const float4 r0v = *(const float4*)(&rowJ[(jb + 0) * 132 + k4 * 4]);
            const float4 r1v = *(const float4*)(&rowJ[(jb + 1) * 132 + k4 * 4]);
            const float4 r2v = *(const float4*)(&rowJ[(jb + 2) * 132 + k4 * 4]);
            const float4 r3v = *(const float4*)(&rowJ[(jb + 3) * 132 + k4 * 4]);
            a0 += w4.x * r0v.x + w4.y * r0v.y + w4.z * r0v.z + w4.w * r0v.w;
            a1 += w4.x * r1v.x + w4.y * r1v.y + w4.z * r1v.z + w4.w * r1v.w;
            a2 += w4.x * r2v.x + w4.y * r2v.y + w4.z * r2v.z + w4.w * r2v.w;
            a3 += w4.x * r3v.x + w4.y * r3v.y + w4.z * r3v.z + w4.w * r3v.w;
        }
        const float vals[4] = { a0 + bc, a1 + bc, a2 + bc, a3 + bc };
#pragma unroll
        for (int j2 = 0; j2 < 4; ++j2) {
            const int rr = r0 + jb + j2;
            if (rr < NN) {
                hpre[(long)rr * FD + c] = vals[j2];
                s1 += vals[j2];
                s2 += vals[j2] * vals[j2];
            }
        }
    }
    red[t] = s1;
    __syncthreads();
    float S1 = 0.f;
    if (t < 128) S1 = red[t] + red[t + 128];
    __syncthreads();
    red[t] = s2;
    __syncthreads();
    if (t < 128) {
        const float S2 = red[t] + red[t + 128];
        atomicAdd(&colsum[c], S1);
        atomicAdd(&colsq[c], S2);
    }
}

// ============ BN + relu + sigmoid + per-graph pooled sums (layer 2) ========
__global__ __launch_bounds__(256) void norm_pool_kernel(
    const float* __restrict__ hpre, const float* __restrict__ cs,
    const float* __restrict__ cq, const float* __restrict__ ga,
    const float* __restrict__ bb, const int* __restrict__ batch,
    float* __restrict__ pooled)
{
    __shared__ float pl[NG * FD];
    const int t = threadIdx.x;
    const int c = t & 127;
    const int half = t >> 7;
    const int r0 = blockIdx.x * 128;
    const int rend = min(r0 + 128, NN);
    const int gmin = batch[r0];
    const int gmax = batch[rend - 1];
    const int span = gmax - gmin + 1;
    for (int i = t; i < span * FD; i += 256) pl[i] = 0.f;
    __syncthreads();
    const float invN = 1.0f / (float)NN;
    const float m = cs[c] * invN;
    const float iv = rsqrtf(cq[c] * invN - m * m + EPSV);
    const float gg = ga[c];
    const float bt = bb[c];
    for (int ir = half; ir < 128; ir += 2) {
        const int r = r0 + ir;
        if (r >= rend) break;
        float v = (hpre[(long)r * FD + c] - m) * iv * gg + bt;
        v = sigf(fmaxf(v, 0.f));
        atomicAdd(&pl[(batch[r] - gmin) * FD + c], v);
    }
    __syncthreads();
    for (int i = t; i < span * FD; i += 256) atomicAdd(&pooled[gmin * FD + i], pl[i]);
}

__device__ __forceinline__ int lbound(const int* __restrict__ a, int n, int v)
{
    int lo = 0, hi = n;
    while (lo < hi) { const int mid = (lo + hi) >> 1; if (a[mid] < v) lo = mid + 1; else hi = mid; }
    return lo;
}

// ============ action MLP head, single block ================================
__global__ __launch_bounds__(256) void mlp_kernel(
    const float* __restrict__ pooled, const int* __restrict__ batch,
    const float* __restrict__ A1w, const float* __restrict__ A1b,
    const float* __restrict__ Ag1, const float* __restrict__ Ab1,
    const float* __restrict__ A2w, const float* __restrict__ A2b,
    const float* __restrict__ Ag2, const float* __restrict__ Ab2,
    const float* __restrict__ A3w, const float* __restrict__ A3b,
    float* __restrict__ out)
{
    __shared__ float Z[NG * FD];
    __shared__ float red[256];
    __shared__ float ml[128], il[128];
    __shared__ float cr[NG];
    const int t = threadIdx.x;
    const int c = t & 127;
    const int half = t >> 7;
    if (t < NG) {
        const int lo = lbound(batch, NN, t);
        const int hi = lbound(batch, NN, t + 1);
        cr[t] = 1.0f / fmaxf((float)(hi - lo), 1.0f);
    }
    __syncthreads();
    float z[32];
    float s1 = 0.f, s2 = 0.f;
    {
        const float bc = A1b[c];
        const float4* wp = (const float4*)(A1w + c * FD);
        for (int ii = 0; ii < 32; ++ii) {
            const int gi = half + 2 * ii;
            const float4* pp = (const float4*)(pooled + gi * FD);
            float d = 0.f;
#pragma unroll 8
            for (int k4 = 0; k4 < 32; ++k4) {
                const float4 w4 = wp[k4];
                const float4 p4 = pp[k4];
                d += w4.x * p4.x + w4.y * p4.y + w4.z * p4.z + w4.w * p4.w;
            }
            const float a = fmaf(d, cr[gi], bc);
            z[ii] = a; s1 += a; s2 += a * a;
        }
    }
    red[t] = s1; __syncthreads();
    if (t < 128) ml[c] = (red[t] + red[t + 128]) * (1.0f / NG);
    __syncthreads();
    red[t] = s2; __syncthreads();
    if (t < 128) {
        const float ms = (red[t] + red[t + 128]) * (1.0f / NG);
        const float mm = ml[c];
        il[c] = rsqrtf(ms - mm * mm + EPSV);
    }
    __syncthreads();
    {
        const float mm = ml[c], iv = il[c], gg = Ag1[c], bb = Ab1[c];
        for (int ii = 0; ii < 32; ++ii) {
            const int gi = half + 2 * ii;
            Z[gi * FD + c] = fmaxf((z[ii] - mm) * iv * gg + bb, 0.f);
        }
    }
    __syncthreads();
    s1 = 0.f; s2 = 0.f;
    {
        const float bc = A2b[c];
        const float4* wp = (const float4*)(A2w + c * FD);
        for (int ii = 0; ii < 32; ++ii) {
            const int gi = half + 2 * ii;
            const float4* pp = (const float4*)(&Z[gi * FD]);
            float d = bc;
#pragma unroll 8
            for (int k4 = 0; k4 < 32; ++k4) {
                const float4 w4 = wp[k4];
                const float4 p4 = pp[k4];
                d += w4.x * p4.x + w4.y * p4.y + w4.z * p4.z + w4.w * p4.w;
            }
            z[ii] = d; s1 += d; s2 += d * d;
        }
    }
    red[t] = s1; __syncthreads();
    if (t < 128) ml[c] = (red[t] + red[t + 128]) * (1.0f / NG);
    __syncthreads();
    red[t] = s2; __syncthreads();
    if (t < 128) {
        const float ms = (red[t] + red[t + 128]) * (1.0f / NG);
        const float mm = ml[c];
        il[c] = rsqrtf(ms - mm * mm + EPSV);
    }
    __syncthreads();
    {
        const float mm = ml[c], iv = il[c], gg = Ag2[c], bb = Ab2[c];
        for (int ii = 0; ii < 32; ++ii) {
            const int gi = half + 2 * ii;
            Z[gi * FD + c] = fmaxf((z[ii] - mm) * iv * gg + bb, 0.f);
        }
    }
    __syncthreads();
    for (int i = t; i < NG * NA; i += 256) {
        const int gi = i >> 4;
        const int a = i & 15;
        const float4* wp = (const float4*)(A3w + a * FD);
        const float4* pp = (const float4*)(&Z[gi * FD]);
        float d = A3b[a];
#pragma unroll 8
        for (int k4 = 0; k4 < 32; ++k4) {
            const float4 w4 = wp[k4];
            const float4 p4 = pp[k4];
            d += w4.x * p4.x + w4.y * p4.y + w4.z * p4.z + w4.w * p4.w;
        }
        out[i] = sigf(d);
    }
}

extern "C" void kernel_launch(void* const* d_in, const int* in_sizes, int n_in,
                              void* d_out, int out_size, void* d_ws, size_t ws_size,
                              hipStream_t stream)
{
    const float* x     = (const float*)d_in[0];
    const float* ea    = (const float*)d_in[1];
    const int*   ei    = (const int*)d_in[2];
    const int*   batch = (const int*)d_in[3];
    const float* W1  = (const float*)d_in[4];
    const float* b1  = (const float*)d_in[5];
    const float* We1 = (const float*)d_in[6];
    const float* be1 = (const float*)d_in[7];
    const float* g1  = (const float*)d_in[8];
    const float* bt1 = (const float*)d_in[9];
    const float* W2  = (const float*)d_in[10];
    const float* b2  = (const float*)d_in[11];
    const float* We2 = (const float*)d_in[12];
    const float* be2 = (const float*)d_in[13];
    const float* g2  = (const float*)d_in[14];
    const float* bt2 = (const float*)d_in[15];
    const float* A1w = (const float*)d_in[16];
    const float* A1b = (const float*)d_in[17];
    const float* Ag1 = (const float*)d_in[18];
    const float* Ab1 = (const float*)d_in[19];
    const float* A2w = (const float*)d_in[20];
    const float* A2b = (const float*)d_in[21];
    const float* Ag2 = (const float*)d_in[22];
    const float* Ab2 = (const float*)d_in[23];
    const float* A3w = (const float*)d_in[24];
    const float* A3b = (const float*)d_in[25];
    float* out = (float*)d_out;

    float* ws      = (float*)d_ws;
    float* xpa     = ws;                       // [NN*FD]
    float* hpre    = ws + (long)NN * FD;       // [NN*FD]
    float* stats   = ws + 2L * NN * FD;        // 512 + NG*FD floats
    float* colsum1 = stats;
    float* colsq1  = stats + 128;
    float* colsum2 = stats + 256;
    float* colsq2  = stats + 384;
    float* pooled  = stats + 512;
    int*   ibase   = (int*)(stats + 512 + NG * FD);  // byte offset divisible by 8
    int2*  perm    = (int2*)ibase;             // [NE]
    int*   off     = ibase + 2 * NE;           // [NN+2]
    int*   cur     = off + NN + 2;             // [NN]
    int*   chunk   = cur + NN;                 // [256]

    hipMemsetAsync(off, 0, (NN + 2) * sizeof(int), stream);
    hipMemsetAsync(stats, 0, (512 + NG * FD) * sizeof(float), stream);

    // CSR build (once; shared by both stages)
    count_kernel<<<NE / 256, 256, 0, stream>>>(ei, off);
    scan1_kernel<<<NCH, 256, 0, stream>>>(off, chunk);
    scan2_kernel<<<1, 256, 0, stream>>>(chunk);
    scan3_kernel<<<NCH, 256, 0, stream>>>(off, cur, chunk);
    scatter_kernel<<<NE / 256, 256, 0, stream>>>(ei, cur, perm);

    // stage 1
    edge_agg_kernel<false><<<NN / 2, 256, 0, stream>>>(
        x, nullptr, nullptr, nullptr, nullptr, ea, off, perm, We1, be1, xpa);
    node_kernel<<<512, 256, 0, stream>>>(xpa, W1, b1, hpre, colsum1, colsq1);

    // stage 2 (BN+relu of stage 1 fused into the gather)
    edge_agg_kernel<true><<<NN / 2, 256, 0, stream>>>(
        hpre, colsum1, colsq1, g1, bt1, ea, off, perm, We2, be2, xpa);
    node_kernel<<<512, 256, 0, stream>>>(xpa, W2, b2, hpre, colsum2, colsq2);

    norm_pool_kernel<<<(NN + 127) / 128, 256, 0, stream>>>(
        hpre, colsum2, colsq2, g2, bt2, batch, pooled);
    mlp_kernel<<<1, 256, 0, stream>>>(pooled, batch, A1w, A1b, Ag1, Ab1,
                                      A2w, A2b, Ag2, Ab2, A3w, A3b, out);
}

// Round 3
// 1308.208 us; speedup vs baseline: 1.4463x; 1.4463x over previous
//
#include <hip/hip_runtime.h>
#include <math.h>

#define NN 50000
#define NE 800000
#define FD 128
#define EDD 32
#define NG 64
#define NA 16
#define EPSV 1e-5f
#define NCH 196            // ceil(NN/256) chunks for the scan
#define EC 32              // edges staged per chunk per node-wave

__device__ __forceinline__ float sigf(float v) { return 1.0f / (1.0f + __expf(-v)); }

// ============ counting sort of edges by dst (CSR build) ====================
__global__ __launch_bounds__(256) void count_kernel(const int* __restrict__ ei,
                                                    int* __restrict__ off)
{
    const int e = blockIdx.x * 256 + threadIdx.x;
    atomicAdd(&off[ei[NE + e]], 1);
}

__global__ __launch_bounds__(256) void scan1_kernel(const int* __restrict__ off,
                                                    int* __restrict__ chunk)
{
    __shared__ int red[256];
    const int i = blockIdx.x * 256 + threadIdx.x;
    red[threadIdx.x] = (i < NN) ? off[i] : 0;
    __syncthreads();
    for (int o = 128; o > 0; o >>= 1) {
        if (threadIdx.x < o) red[threadIdx.x] += red[threadIdx.x + o];
        __syncthreads();
    }
    if (threadIdx.x == 0) chunk[blockIdx.x] = red[0];
}

__global__ __launch_bounds__(256) void scan2_kernel(int* __restrict__ chunk)
{
    __shared__ int sh[256];
    const int t = threadIdx.x;
    const int v = (t < NCH) ? chunk[t] : 0;
    sh[t] = v;
    __syncthreads();
    for (int o = 1; o < 256; o <<= 1) {
        int x = (t >= o) ? sh[t - o] : 0;
        __syncthreads();
        sh[t] += x;
        __syncthreads();
    }
    if (t < NCH) chunk[t] = sh[t] - v;
}

__global__ __launch_bounds__(256) void scan3_kernel(int* __restrict__ off,
                                                    int* __restrict__ cur,
                                                    const int* __restrict__ chunk)
{
    __shared__ int sh[256];
    const int t = threadIdx.x;
    const int i = blockIdx.x * 256 + t;
    const int v = (i < NN) ? off[i] : 0;
    sh[t] = v;
    __syncthreads();
    for (int o = 1; o < 256; o <<= 1) {
        int x = (t >= o) ? sh[t - o] : 0;
        __syncthreads();
        sh[t] += x;
        __syncthreads();
    }
    const int ex = sh[t] - v + chunk[blockIdx.x];
    if (i < NN) { off[i] = ex; cur[i] = ex; }
    if (i == 0) off[NN] = NE;
}

__global__ __launch_bounds__(256) void scatter_kernel(const int* __restrict__ ei,
                                                      int* __restrict__ cur,
                                                      int2* __restrict__ perm)
{
    const int e = blockIdx.x * 256 + threadIdx.x;
    const int src = ei[e];
    const int dst = ei[NE + e];
    const int pos = atomicAdd(&cur[dst], 1);
    perm[pos] = make_int2(src, e);
}

// ============ gather-style edge stage, one wave per node ===================
// xpa[n] = tr(x[n]) + sum_{e: dst=n} relu(tr(x[src_e]) + ea_e @ We^T + be)
// Wave = 64 lanes; lane l owns channels l and l+64 (We rows in registers).
// Edge attrs staged per-chunk into LDS via coalesced per-lane float4 gathers.
template<bool TR>
__global__ __launch_bounds__(256) void edge_agg_kernel(
    const float* __restrict__ xin, const float* __restrict__ cs,
    const float* __restrict__ cq, const float* __restrict__ ga,
    const float* __restrict__ bb, const float* __restrict__ eattr,
    const int* __restrict__ off, const int2* __restrict__ perm,
    const float* __restrict__ We, const float* __restrict__ be,
    float* __restrict__ xpa)
{
    __shared__ float ea_s[4][EC * EDD];   // 16 KB
    __shared__ int   src_s[4][EC];
    __shared__ int   dmax_s[4];
    const int t = threadIdx.x;
    const int w = t >> 6;
    const int l = t & 63;
    const int node = blockIdx.x * 4 + w;

    float w0[EDD], w1[EDD];
    {
        const float4* a  = (const float4*)(We + l * EDD);
        const float4* b2 = (const float4*)(We + (l + 64) * EDD);
#pragma unroll
        for (int i = 0; i < 8; ++i) {
            const float4 va = a[i], vb = b2[i];
            w0[4*i+0]=va.x; w0[4*i+1]=va.y; w0[4*i+2]=va.z; w0[4*i+3]=va.w;
            w1[4*i+0]=vb.x; w1[4*i+1]=vb.y; w1[4*i+2]=vb.z; w1[4*i+3]=vb.w;
        }
    }
    const float be0 = be[l], be1 = be[l + 64];
    float A0 = 1.f, B0 = 0.f, A1 = 1.f, B1 = 0.f;
    if (TR) {
        const float invN = 1.0f / (float)NN;
        { const float m = cs[l] * invN;
          const float iv = rsqrtf(cq[l] * invN - m * m + EPSV);
          A0 = iv * ga[l]; B0 = bb[l] - m * A0; }
        { const float m = cs[l + 64] * invN;
          const float iv = rsqrtf(cq[l + 64] * invN - m * m + EPSV);
          A1 = iv * ga[l + 64]; B1 = bb[l + 64] - m * A1; }
    }
    const int lo = off[node], hi = off[node + 1];
    if (l == 0) dmax_s[w] = hi - lo;
    const float xa = xin[(long)node * FD + l];
    const float xb = xin[(long)node * FD + 64 + l];
    float acc0 = TR ? fmaxf(fmaf(xa, A0, B0), 0.f) : xa;
    float acc1 = TR ? fmaxf(fmaf(xb, A1, B1), 0.f) : xb;
    __syncthreads();
    const int dmax = max(max(dmax_s[0], dmax_s[1]), max(dmax_s[2], dmax_s[3]));
    const int nch = (dmax + EC - 1) / EC;          // uniform across block

    for (int ch = 0; ch < nch; ++ch) {
        const int base = lo + ch * EC;
        const int n = min(EC, hi - base);          // may be <= 0 for this wave
        // stage src ids (lanes 0..EC-1, coalesced)
        if (l < EC && l < n) src_s[w][l] = perm[base + l].x;
        // stage edge attrs: 8 lanes per edge row, 4 rounds
        {
            const int p = l & 7;
#pragma unroll
            for (int r = 0; r < 4; ++r) {
                const int jj = (l >> 3) + 8 * r;
                if (jj < n) {
                    const int e = perm[base + jj].y;
                    const float4 v = *(const float4*)(eattr + (long)e * EDD + p * 4);
                    *(float4*)(&ea_s[w][jj * EDD + p * 4]) = v;
                }
            }
        }
        __syncthreads();
        // compute, x-row loads pipelined one edge ahead
        if (n > 0) {
            int src = src_s[w][0];
            float xs0 = xin[(long)src * FD + l];
            float xs1 = xin[(long)src * FD + 64 + l];
            for (int j = 0; j < n; ++j) {
                float nx0 = 0.f, nx1 = 0.f;
                if (j + 1 < n) {
                    const int sn = src_s[w][j + 1];
                    nx0 = xin[(long)sn * FD + l];
                    nx1 = xin[(long)sn * FD + 64 + l];
                }
                float m0 = be0, m1 = be1;
                const float4* ev = (const float4*)(&ea_s[w][j * EDD]);
#pragma unroll
                for (int k = 0; k < 8; ++k) {
                    const float4 v = ev[k];
                    m0 = fmaf(v.x, w0[4*k+0], m0);
                    m0 = fmaf(v.y, w0[4*k+1], m0);
                    m0 = fmaf(v.z, w0[4*k+2], m0);
                    m0 = fmaf(v.w, w0[4*k+3], m0);
                    m1 = fmaf(v.x, w1[4*k+0], m1);
                    m1 = fmaf(v.y, w1[4*k+1], m1);
                    m1 = fmaf(v.z, w1[4*k+2], m1);
                    m1 = fmaf(v.w, w1[4*k+3], m1);
                }
                const float t0 = TR ? fmaxf(fmaf(xs0, A0, B0), 0.f) : xs0;
                const float t1 = TR ? fmaxf(fmaf(xs1, A1, B1), 0.f) : xs1;
                acc0 += fmaxf(m0 + t0, 0.f);
                acc1 += fmaxf(m1 + t1, 0.f);
                xs0 = nx0; xs1 = nx1;
            }
        }
        if (ch + 1 < nch) __syncthreads();
    }
    xpa[(long)node * FD + l]      = acc0;
    xpa[(long)node * FD + 64 + l] = acc1;
}

// ============ node GEMM: hpre = xpa @ W^T + b, fused BN column stats =======
// W row per thread held in registers (loaded once), k-loop fully unrolled.
__global__ __launch_bounds__(256) void node_kernel(
    const float* __restrict__ xpa, const float* __restrict__ W,
    const float* __restrict__ b, float* __restrict__ hpre,
    float* __restrict__ colsum, float* __restrict__ colsq)
{
    __shared__ float rowJ[8 * 132];
    __shared__ float red[256];
    const int t = threadIdx.x;
    const int c = t & 127;
    const int half = t >> 7;
    const int js = t & 7;
    const int kk = t >> 3;
    const float bc = b[c];
    float4 wr[32];
    {
        const float4* wp = (const float4*)(W + c * FD);
#pragma unroll
        for (int i = 0; i < 32; ++i) wr[i] = wp[i];
    }
    float s1 = 0.0f, s2 = 0.0f;
    const int stride = gridDim.x * 8;
    const int iters = (NN + stride - 1) / stride;
    for (int it = 0; it < iters; ++it) {
        const int r0 = (blockIdx.x + it * gridDim.x) * 8;
        __syncthreads();
        {
            const int r = r0 + js;
            float4 v = make_float4(0.f, 0.f, 0.f, 0.f);
            if (r < NN) v = *(const float4*)(xpa + (long)r * FD + kk * 4);
            *(float4*)(&rowJ[js * 132 + kk * 4]) = v;
        }
        __syncthreads();
        float a0 = 0.f, a1 = 0.f, a2 = 0.f, a3 = 0.f;
        const int jb = half * 4;
#pragma unroll
        for (int k4 = 0; k4 < 32; ++k4) {
            const float4 w4 = wr[k4];
            const float4 r0v = *(const float4*)(&rowJ[(jb + 0) * 132 + k4 * 4]);
            const float4 r1v = *(const float4*)(&rowJ[(jb + 1) * 132 + k4 * 4]);
            const float4 r2v = *(const float4*)(&rowJ[(jb + 2) * 132 + k4 * 4]);
            const float4 r3v = *(const float4*)(&rowJ[(jb + 3) * 132 + k4 * 4]);
            a0 += w4.x * r0v.x + w4.y * r0v.y + w4.z * r0v.z + w4.w * r0v.w;
            a1 += w4.x * r1v.x + w4.y * r1v.y + w4.z * r1v.z + w4.w * r1v.w;
            a2 += w4.x * r2v.x + w4.y * r2v.y + w4.z * r2v.z + w4.w * r2v.w;
            a3 += w4.x * r3v.x + w4.y * r3v.y + w4.z * r3v.z + w4.w * r3v.w;
        }
        const float vals[4] = { a0 + bc, a1 + bc, a2 + bc, a3 + bc };
#pragma unroll
        for (int j2 = 0; j2 < 4; ++j2) {
            const int rr = r0 + jb + j2;
            if (rr < NN) {
                hpre[(long)rr * FD + c] = vals[j2];
                s1 += vals[j2];
                s2 += vals[j2] * vals[j2];
            }
        }
    }
    red[t] = s1;
    __syncthreads();
    float S1 = 0.f;
    if (t < 128) S1 = red[t] + red[t + 128];
    __syncthreads();
    red[t] = s2;
    __syncthreads();
    if (t < 128) {
        const float S2 = red[t] + red[t + 128];
        atomicAdd(&colsum[c], S1);
        atomicAdd(&colsq[c], S2);
    }
}

// ============ BN + relu + sigmoid + per-graph pooled sums (layer 2) ========
__global__ __launch_bounds__(256) void norm_pool_kernel(
    const float* __restrict__ hpre, const float* __restrict__ cs,
    const float* __restrict__ cq, const float* __restrict__ ga,
    const float* __restrict__ bb, const int* __restrict__ batch,
    float* __restrict__ pooled)
{
    __shared__ float pl[NG * FD];
    const int t = threadIdx.x;
    const int c = t & 127;
    const int half = t >> 7;
    const int r0 = blockIdx.x * 128;
    const int rend = min(r0 + 128, NN);
    const int gmin = batch[r0];
    const int gmax = batch[rend - 1];
    const int span = gmax - gmin + 1;
    for (int i = t; i < span * FD; i += 256) pl[i] = 0.f;
    __syncthreads();
    const float invN = 1.0f / (float)NN;
    const float m = cs[c] * invN;
    const float iv = rsqrtf(cq[c] * invN - m * m + EPSV);
    const float gg = ga[c];
    const float bt = bb[c];
    for (int ir = half; ir < 128; ir += 2) {
        const int r = r0 + ir;
        if (r >= rend) break;
        float v = (hpre[(long)r * FD + c] - m) * iv * gg + bt;
        v = sigf(fmaxf(v, 0.f));
        atomicAdd(&pl[(batch[r] - gmin) * FD + c], v);
    }
    __syncthreads();
    for (int i = t; i < span * FD; i += 256) atomicAdd(&pooled[gmin * FD + i], pl[i]);
}

__device__ __forceinline__ int lbound(const int* __restrict__ a, int n, int v)
{
    int lo = 0, hi = n;
    while (lo < hi) { const int mid = (lo + hi) >> 1; if (a[mid] < v) lo = mid + 1; else hi = mid; }
    return lo;
}

// ============ action MLP head, single block ================================
__global__ __launch_bounds__(256) void mlp_kernel(
    const float* __restrict__ pooled, const int* __restrict__ batch,
    const float* __restrict__ A1w, const float* __restrict__ A1b,
    const float* __restrict__ Ag1, const float* __restrict__ Ab1,
    const float* __restrict__ A2w, const float* __restrict__ A2b,
    const float* __restrict__ Ag2, const float* __restrict__ Ab2,
    const float* __restrict__ A3w, const float* __restrict__ A3b,
    float* __restrict__ out)
{
    __shared__ float Z[NG * FD];
    __shared__ float red[256];
    __shared__ float ml[128], il[128];
    __shared__ float cr[NG];
    const int t = threadIdx.x;
    const int c = t & 127;
    const int half = t >> 7;
    if (t < NG) {
        const int lo = lbound(batch, NN, t);
        const int hi = lbound(batch, NN, t + 1);
        cr[t] = 1.0f / fmaxf((float)(hi - lo), 1.0f);
    }
    __syncthreads();
    float z[32];
    float s1 = 0.f, s2 = 0.f;
    {
        const float bc = A1b[c];
        const float4* wp = (const float4*)(A1w + c * FD);
        for (int ii = 0; ii < 32; ++ii) {
            const int gi = half + 2 * ii;
            const float4* pp = (const float4*)(pooled + gi * FD);
            float d = 0.f;
#pragma unroll 8
            for (int k4 = 0; k4 < 32; ++k4) {
                const float4 w4 = wp[k4];
                const float4 p4 = pp[k4];
                d += w4.x * p4.x + w4.y * p4.y + w4.z * p4.z + w4.w * p4.w;
            }
            const float a = fmaf(d, cr[gi], bc);
            z[ii] = a; s1 += a; s2 += a * a;
        }
    }
    red[t] = s1; __syncthreads();
    if (t < 128) ml[c] = (red[t] + red[t + 128]) * (1.0f / NG);
    __syncthreads();
    red[t] = s2; __syncthreads();
    if (t < 128) {
        const float ms = (red[t] + red[t + 128]) * (1.0f / NG);
        const float mm = ml[c];
        il[c] = rsqrtf(ms - mm * mm + EPSV);
    }
    __syncthreads();
    {
        const float mm = ml[c], iv = il[c], gg = Ag1[c], bb = Ab1[c];
        for (int ii = 0; ii < 32; ++ii) {
            const int gi = half + 2 * ii;
            Z[gi * FD + c] = fmaxf((z[ii] - mm) * iv * gg + bb, 0.f);
        }
    }
    __syncthreads();
    s1 = 0.f; s2 = 0.f;
    {
        const float bc = A2b[c];
        const float4* wp = (const float4*)(A2w + c * FD);
        for (int ii = 0; ii < 32; ++ii) {
            const int gi = half + 2 * ii;
            const float4* pp = (const float4*)(&Z[gi * FD]);
            float d = bc;
#pragma unroll 8
            for (int k4 = 0; k4 < 32; ++k4) {
                const float4 w4 = wp[k4];
                const float4 p4 = pp[k4];
                d += w4.x * p4.x + w4.y * p4.y + w4.z * p4.z + w4.w * p4.w;
            }
            z[ii] = d; s1 += d; s2 += d * d;
        }
    }
    red[t] = s1; __syncthreads();
    if (t < 128) ml[c] = (red[t] + red[t + 128]) * (1.0f / NG);
    __syncthreads();
    red[t] = s2; __syncthreads();
    if (t < 128) {
        const float ms = (red[t] + red[t + 128]) * (1.0f / NG);
        const float mm = ml[c];
        il[c] = rsqrtf(ms - mm * mm + EPSV);
    }
    __syncthreads();
    {
        const float mm = ml[c], iv = il[c], gg = Ag2[c], bb = Ab2[c];
        for (int ii = 0; ii < 32; ++ii) {
            const int gi = half + 2 * ii;
            Z[gi * FD + c] = fmaxf((z[ii] - mm) * iv * gg + bb, 0.f);
        }
    }
    __syncthreads();
    for (int i = t; i < NG * NA; i += 256) {
        const int gi = i >> 4;
        const int a = i & 15;
        const float4* wp = (const float4*)(A3w + a * FD);
        const float4* pp = (const float4*)(&Z[gi * FD]);
        float d = A3b[a];
#pragma unroll 8
        for (int k4 = 0; k4 < 32; ++k4) {
            const float4 w4 = wp[k4];
            const float4 p4 = pp[k4];
            d += w4.x * p4.x + w4.y * p4.y + w4.z * p4.z + w4.w * p4.w;
        }
        out[i] = sigf(d);
    }
}

extern "C" void kernel_launch(void* const* d_in, const int* in_sizes, int n_in,
                              void* d_out, int out_size, void* d_ws, size_t ws_size,
                              hipStream_t stream)
{
    const float* x     = (const float*)d_in[0];
    const float* ea    = (const float*)d_in[1];
    const int*   ei    = (const int*)d_in[2];
    const int*   batch = (const int*)d_in[3];
    const float* W1  = (const float*)d_in[4];
    const float* b1  = (const float*)d_in[5];
    const float* We1 = (const float*)d_in[6];
    const float* be1 = (const float*)d_in[7];
    const float* g1  = (const float*)d_in[8];
    const float* bt1 = (const float*)d_in[9];
    const float* W2  = (const float*)d_in[10];
    const float* b2  = (const float*)d_in[11];
    const float* We2 = (const float*)d_in[12];
    const float* be2 = (const float*)d_in[13];
    const float* g2  = (const float*)d_in[14];
    const float* bt2 = (const float*)d_in[15];
    const float* A1w = (const float*)d_in[16];
    const float* A1b = (const float*)d_in[17];
    const float* Ag1 = (const float*)d_in[18];
    const float* Ab1 = (const float*)d_in[19];
    const float* A2w = (const float*)d_in[20];
    const float* A2b = (const float*)d_in[21];
    const float* Ag2 = (const float*)d_in[22];
    const float* Ab2 = (const float*)d_in[23];
    const float* A3w = (const float*)d_in[24];
    const float* A3b = (const float*)d_in[25];
    float* out = (float*)d_out;

    float* ws      = (float*)d_ws;
    float* xpa     = ws;                       // [NN*FD]
    float* hpre    = ws + (long)NN * FD;       // [NN*FD]
    float* stats   = ws + 2L * NN * FD;        // 512 + NG*FD floats
    float* colsum1 = stats;
    float* colsq1  = stats + 128;
    float* colsum2 = stats + 256;
    float* colsq2  = stats + 384;
    float* pooled  = stats + 512;
    int*   ibase   = (int*)(stats + 512 + NG * FD);
    int2*  perm    = (int2*)ibase;             // [NE]
    int*   off     = ibase + 2 * NE;           // [NN+2]
    int*   cur     = off + NN + 2;             // [NN]
    int*   chunk   = cur + NN;                 // [256]

    hipMemsetAsync(off, 0, (NN + 2) * sizeof(int), stream);
    hipMemsetAsync(stats, 0, (512 + NG * FD) * sizeof(float), stream);

    // CSR build (once; shared by both stages)
    count_kernel<<<NE / 256, 256, 0, stream>>>(ei, off);
    scan1_kernel<<<NCH, 256, 0, stream>>>(off, chunk);
    scan2_kernel<<<1, 256, 0, stream>>>(chunk);
    scan3_kernel<<<NCH, 256, 0, stream>>>(off, cur, chunk);
    scatter_kernel<<<NE / 256, 256, 0, stream>>>(ei, cur, perm);

    // stage 1
    edge_agg_kernel<false><<<NN / 4, 256, 0, stream>>>(
        x, nullptr, nullptr, nullptr, nullptr, ea, off, perm, We1, be1, xpa);
    node_kernel<<<512, 256, 0, stream>>>(xpa, W1, b1, hpre, colsum1, colsq1);

    // stage 2 (BN+relu of stage 1 fused into the gather)
    edge_agg_kernel<true><<<NN / 4, 256, 0, stream>>>(
        hpre, colsum1, colsq1, g1, bt1, ea, off, perm, We2, be2, xpa);
    node_kernel<<<512, 256, 0, stream>>>(xpa, W2, b2, hpre, colsum2, colsq2);

    norm_pool_kernel<<<(NN + 127) / 128, 256, 0, stream>>>(
        hpre, colsum2, colsq2, g2, bt2, batch, pooled);
    mlp_kernel<<<1, 256, 0, stream>>>(pooled, batch, A1w, A1b, Ag1, Ab1,
                                      A2w, A2b, Ag2, Ab2, A3w, A3b, out);
}

// Round 4
// 1137.417 us; speedup vs baseline: 1.6634x; 1.1502x over previous
//
#include <hip/hip_runtime.h>
#include <math.h>

#define NN 50000
#define NE 800000
#define FD 128
#define EDD 32
#define NG 64
#define NA 16
#define EPSV 1e-5f
#define NCH 196            // ceil(NN/256) chunks for the scan
#define EC 32              // edges staged per chunk per node-wave

__device__ __forceinline__ float sigf(float v) { return 1.0f / (1.0f + __expf(-v)); }

// ============ counting sort of edges by dst (CSR build) ====================
__global__ __launch_bounds__(256) void count_kernel(const int* __restrict__ ei,
                                                    int* __restrict__ off)
{
    const int e = blockIdx.x * 256 + threadIdx.x;
    atomicAdd(&off[ei[NE + e]], 1);
}

__global__ __launch_bounds__(256) void scan1_kernel(const int* __restrict__ off,
                                                    int* __restrict__ chunk)
{
    __shared__ int red[256];
    const int i = blockIdx.x * 256 + threadIdx.x;
    red[threadIdx.x] = (i < NN) ? off[i] : 0;
    __syncthreads();
    for (int o = 128; o > 0; o >>= 1) {
        if (threadIdx.x < o) red[threadIdx.x] += red[threadIdx.x + o];
        __syncthreads();
    }
    if (threadIdx.x == 0) chunk[blockIdx.x] = red[0];
}

__global__ __launch_bounds__(256) void scan2_kernel(int* __restrict__ chunk)
{
    __shared__ int sh[256];
    const int t = threadIdx.x;
    const int v = (t < NCH) ? chunk[t] : 0;
    sh[t] = v;
    __syncthreads();
    for (int o = 1; o < 256; o <<= 1) {
        int x = (t >= o) ? sh[t - o] : 0;
        __syncthreads();
        sh[t] += x;
        __syncthreads();
    }
    if (t < NCH) chunk[t] = sh[t] - v;
}

__global__ __launch_bounds__(256) void scan3_kernel(int* __restrict__ off,
                                                    int* __restrict__ cur,
                                                    const int* __restrict__ chunk)
{
    __shared__ int sh[256];
    const int t = threadIdx.x;
    const int i = blockIdx.x * 256 + t;
    const int v = (i < NN) ? off[i] : 0;
    sh[t] = v;
    __syncthreads();
    for (int o = 1; o < 256; o <<= 1) {
        int x = (t >= o) ? sh[t - o] : 0;
        __syncthreads();
        sh[t] += x;
        __syncthreads();
    }
    const int ex = sh[t] - v + chunk[blockIdx.x];
    if (i < NN) { off[i] = ex; cur[i] = ex; }
    if (i == 0) off[NN] = NE;
}

__global__ __launch_bounds__(256) void scatter_kernel(const int* __restrict__ ei,
                                                      int* __restrict__ cur,
                                                      int2* __restrict__ perm)
{
    const int e = blockIdx.x * 256 + threadIdx.x;
    const int src = ei[e];
    const int dst = ei[NE + e];
    const int pos = atomicAdd(&cur[dst], 1);
    perm[pos] = make_int2(src, e);
}

// ============ gather-style edge stage, one wave per node ===================
// xpa[n] = tr(x[n]) + sum_{e: dst=n} relu(tr(x[src_e]) + ea_e @ We^T + be)
// Wave-independent (no block barriers): each wave stages its own edges into
// its own LDS region; x[src] rows pipelined 4 edges deep.
template<bool TR>
__global__ __launch_bounds__(256) void edge_agg_kernel(
    const float* __restrict__ xin, const float* __restrict__ cs,
    const float* __restrict__ cq, const float* __restrict__ ga,
    const float* __restrict__ bb, const float* __restrict__ eattr,
    const int* __restrict__ off, const int2* __restrict__ perm,
    const float* __restrict__ We, const float* __restrict__ be,
    float* __restrict__ xpa)
{
    __shared__ float ea_s[4][EC * EDD];   // 16 KB
    __shared__ int   src_s[4][EC];
    const int t = threadIdx.x;
    const int w = t >> 6;
    const int l = t & 63;
    const int node = blockIdx.x * 4 + w;

    float w0[EDD], w1[EDD];
    {
        const float4* a  = (const float4*)(We + l * EDD);
        const float4* b2 = (const float4*)(We + (l + 64) * EDD);
#pragma unroll
        for (int i = 0; i < 8; ++i) {
            const float4 va = a[i], vb = b2[i];
            w0[4*i+0]=va.x; w0[4*i+1]=va.y; w0[4*i+2]=va.z; w0[4*i+3]=va.w;
            w1[4*i+0]=vb.x; w1[4*i+1]=vb.y; w1[4*i+2]=vb.z; w1[4*i+3]=vb.w;
        }
    }
    const float be0 = be[l], be1 = be[l + 64];
    float A0 = 1.f, B0 = 0.f, A1 = 1.f, B1 = 0.f;
    if (TR) {
        const float invN = 1.0f / (float)NN;
        { const float m = cs[l] * invN;
          const float iv = rsqrtf(cq[l] * invN - m * m + EPSV);
          A0 = iv * ga[l]; B0 = bb[l] - m * A0; }
        { const float m = cs[l + 64] * invN;
          const float iv = rsqrtf(cq[l + 64] * invN - m * m + EPSV);
          A1 = iv * ga[l + 64]; B1 = bb[l + 64] - m * A1; }
    }
    const int lo = off[node], hi = off[node + 1];
    const float xa = xin[(long)node * FD + l];
    const float xb = xin[(long)node * FD + 64 + l];
    float acc0 = TR ? fmaxf(fmaf(xa, A0, B0), 0.f) : xa;
    float acc1 = TR ? fmaxf(fmaf(xb, A1, B1), 0.f) : xb;
    const int nch = (hi - lo + EC - 1) / EC;    // per-wave, no block coupling

    const int p  = l & 7;
    const int jb0 = l >> 3;
    for (int ch = 0; ch < nch; ++ch) {
        const int base = lo + ch * EC;
        const int n = min(EC, hi - base);
        // stage src ids (lanes 0..31, coalesced int2 reads)
        if (l < EC && l < n) src_s[w][l] = perm[base + l].x;
        // stage edge attrs: 8 lanes per edge row, 4 independent rounds
#pragma unroll
        for (int r = 0; r < 4; ++r) {
            const int jj = jb0 + 8 * r;
            if (jj < n) {
                const int e = perm[base + jj].y;
                *(float4*)(&ea_s[w][jj * EDD + p * 4]) =
                    *(const float4*)(eattr + (long)e * EDD + p * 4);
            }
        }
        // x-row pipeline, groups of 4 edges
        float ca0[4], ca1[4], cb0[4], cb1[4];
#pragma unroll
        for (int q = 0; q < 4; ++q) {
            if (q < n) {
                const int s = src_s[w][q];
                ca0[q] = xin[(long)s * FD + l];
                ca1[q] = xin[(long)s * FD + 64 + l];
            } else { ca0[q] = 0.f; ca1[q] = 0.f; }
        }
        const int ng = (n + 3) >> 2;
        for (int g = 0; g < ng; ++g) {
            const int jg = g * 4;
#pragma unroll
            for (int q = 0; q < 4; ++q) {
                const int j = jg + 4 + q;
                if (j < n) {
                    const int s = src_s[w][j];
                    cb0[q] = xin[(long)s * FD + l];
                    cb1[q] = xin[(long)s * FD + 64 + l];
                } else { cb0[q] = 0.f; cb1[q] = 0.f; }
            }
#pragma unroll
            for (int q = 0; q < 4; ++q) {
                const int j = jg + q;
                if (j < n) {
                    float m0 = be0, m1 = be1;
                    const float4* ev = (const float4*)(&ea_s[w][j * EDD]);
#pragma unroll
                    for (int k = 0; k < 8; ++k) {
                        const float4 v = ev[k];
                        m0 = fmaf(v.x, w0[4*k+0], m0);
                        m0 = fmaf(v.y, w0[4*k+1], m0);
                        m0 = fmaf(v.z, w0[4*k+2], m0);
                        m0 = fmaf(v.w, w0[4*k+3], m0);
                        m1 = fmaf(v.x, w1[4*k+0], m1);
                        m1 = fmaf(v.y, w1[4*k+1], m1);
                        m1 = fmaf(v.z, w1[4*k+2], m1);
                        m1 = fmaf(v.w, w1[4*k+3], m1);
                    }
                    const float t0 = TR ? fmaxf(fmaf(ca0[q], A0, B0), 0.f) : ca0[q];
                    const float t1 = TR ? fmaxf(fmaf(ca1[q], A1, B1), 0.f) : ca1[q];
                    acc0 += fmaxf(m0 + t0, 0.f);
                    acc1 += fmaxf(m1 + t1, 0.f);
                }
            }
#pragma unroll
            for (int q = 0; q < 4; ++q) { ca0[q] = cb0[q]; ca1[q] = cb1[q]; }
        }
    }
    xpa[(long)node * FD + l]      = acc0;
    xpa[(long)node * FD + 64 + l] = acc1;
}

// ============ node GEMM: hpre = xpa @ W^T + b, fused BN column stats =======
__global__ __launch_bounds__(256) void node_kernel(
    const float* __restrict__ xpa, const float* __restrict__ W,
    const float* __restrict__ b, float* __restrict__ hpre,
    float* __restrict__ colsum, float* __restrict__ colsq)
{
    __shared__ float rowJ[8 * 132];
    __shared__ float red[256];
    const int t = threadIdx.x;
    const int c = t & 127;
    const int half = t >> 7;
    const int js = t & 7;
    const int kk = t >> 3;
    const float bc = b[c];
    float4 wr[32];
    {
        const float4* wp = (const float4*)(W + c * FD);
#pragma unroll
        for (int i = 0; i < 32; ++i) wr[i] = wp[i];
    }
    float s1 = 0.0f, s2 = 0.0f;
    const int stride = gridDim.x * 8;
    const int iters = (NN + stride - 1) / stride;
    for (int it = 0; it < iters; ++it) {
        const int r0 = (blockIdx.x + it * gridDim.x) * 8;
        __syncthreads();
        {
            const int r = r0 + js;
            float4 v = make_float4(0.f, 0.f, 0.f, 0.f);
            if (r < NN) v = *(const float4*)(xpa + (long)r * FD + kk * 4);
            *(float4*)(&rowJ[js * 132 + kk * 4]) = v;
        }
        __syncthreads();
        float a0 = 0.f, a1 = 0.f, a2 = 0.f, a3 = 0.f;
        const int jb = half * 4;
#pragma unroll
        for (int k4 = 0; k4 < 32; ++k4) {
            const float4 w4 = wr[k4];
            const float4 r0v = *(const float4*)(&rowJ[(jb + 0) * 132 + k4 * 4]);
            const float4 r1v = *(const float4*)(&rowJ[(jb + 1) * 132 + k4 * 4]);
            const float4 r2v = *(const float4*)(&rowJ[(jb + 2) * 132 + k4 * 4]);
            const float4 r3v = *(const float4*)(&rowJ[(jb + 3) * 132 + k4 * 4]);
            a0 += w4.x * r0v.x + w4.y * r0v.y + w4.z * r0v.z + w4.w * r0v.w;
            a1 += w4.x * r1v.x + w4.y * r1v.y + w4.z * r1v.z + w4.w * r1v.w;
            a2 += w4.x * r2v.x + w4.y * r2v.y + w4.z * r2v.z + w4.w * r2v.w;
            a3 += w4.x * r3v.x + w4.y * r3v.y + w4.z * r3v.z + w4.w * r3v.w;
        }
        const float vals[4] = { a0 + bc, a1 + bc, a2 + bc, a3 + bc };
#pragma unroll
        for (int j2 = 0; j2 < 4; ++j2) {
            const int rr = r0 + jb + j2;
            if (rr < NN) {
                hpre[(long)rr * FD + c] = vals[j2];
                s1 += vals[j2];
                s2 += vals[j2] * vals[j2];
            }
        }
    }
    red[t] = s1;
    __syncthreads();
    float S1 = 0.f;
    if (t < 128) S1 = red[t] + red[t + 128];
    __syncthreads();
    red[t] = s2;
    __syncthreads();
    if (t < 128) {
        const float S2 = red[t] + red[t + 128];
        atomicAdd(&colsum[c], S1);
        atomicAdd(&colsq[c], S2);
    }
}

// ============ BN + relu + sigmoid + per-graph pooled sums (layer 2) ========
__global__ __launch_bounds__(256) void norm_pool_kernel(
    const float* __restrict__ hpre, const float* __restrict__ cs,
    const float* __restrict__ cq, const float* __restrict__ ga,
    const float* __restrict__ bb, const int* __restrict__ batch,
    float* __restrict__ pooled)
{
    __shared__ float pl[NG * FD];
    const int t = threadIdx.x;
    const int c = t & 127;
    const int half = t >> 7;
    const int r0 = blockIdx.x * 128;
    const int rend = min(r0 + 128, NN);
    const int gmin = batch[r0];
    const int gmax = batch[rend - 1];
    const int span = gmax - gmin + 1;
    for (int i = t; i < span * FD; i += 256) pl[i] = 0.f;
    __syncthreads();
    const float invN = 1.0f / (float)NN;
    const float m = cs[c] * invN;
    const float iv = rsqrtf(cq[c] * invN - m * m + EPSV);
    const float gg = ga[c];
    const float bt = bb[c];
    for (int ir = half; ir < 128; ir += 2) {
        const int r = r0 + ir;
        if (r >= rend) break;
        float v = (hpre[(long)r * FD + c] - m) * iv * gg + bt;
        v = sigf(fmaxf(v, 0.f));
        atomicAdd(&pl[(batch[r] - gmin) * FD + c], v);
    }
    __syncthreads();
    for (int i = t; i < span * FD; i += 256) atomicAdd(&pooled[gmin * FD + i], pl[i]);
}

__device__ __forceinline__ int lbound(const int* __restrict__ a, int n, int v)
{
    int lo = 0, hi = n;
    while (lo < hi) { const int mid = (lo + hi) >> 1; if (a[mid] < v) lo = mid + 1; else hi = mid; }
    return lo;
}

// ============ action MLP head, single block ================================
// k-chunked register blocking: weight row chunk loaded ONCE, swept across all
// 32 graphs. Z/pooled reads are wave-uniform (broadcast).
__global__ __launch_bounds__(256) void mlp_kernel(
    const float* __restrict__ pooled, const int* __restrict__ batch,
    const float* __restrict__ A1w, const float* __restrict__ A1b,
    const float* __restrict__ Ag1, const float* __restrict__ Ab1,
    const float* __restrict__ A2w, const float* __restrict__ A2b,
    const float* __restrict__ Ag2, const float* __restrict__ Ab2,
    const float* __restrict__ A3w, const float* __restrict__ A3b,
    float* __restrict__ out)
{
    __shared__ float Z[NG * FD];
    __shared__ float red[256];
    __shared__ float ml[128], il[128];
    __shared__ float cr[NG];
    const int t = threadIdx.x;
    const int c = t & 127;
    const int half = t >> 7;
    // wave 0 computes per-graph counts; other waves proceed straight to dots
    if (t < NG) {
        const int lo = lbound(batch, NN, t);
        const int hi = lbound(batch, NN, t + 1);
        cr[t] = 1.0f / fmaxf((float)(hi - lo), 1.0f);
    }
    float acc[32];
#pragma unroll
    for (int ii = 0; ii < 32; ++ii) acc[ii] = 0.f;
    // ---- layer 1 dot: acc[ii] = pooled[gi] . A1w[c] ----
#pragma unroll 1
    for (int kc = 0; kc < 4; ++kc) {
        float4 wr[8];
        const float4* wp = (const float4*)(A1w + c * FD + kc * 32);
#pragma unroll
        for (int i = 0; i < 8; ++i) wr[i] = wp[i];
#pragma unroll
        for (int ii = 0; ii < 32; ++ii) {
            const int gi = half + 2 * ii;
            const float4* pp = (const float4*)(pooled + gi * FD + kc * 32);
            float d = 0.f;
#pragma unroll
            for (int i = 0; i < 8; ++i) {
                const float4 w4 = wr[i], p4 = pp[i];
                d += w4.x * p4.x + w4.y * p4.y + w4.z * p4.z + w4.w * p4.w;
            }
            acc[ii] += d;
        }
    }
    __syncthreads();   // cr ready
    float s1 = 0.f, s2 = 0.f;
    {
        const float bc = A1b[c];
#pragma unroll
        for (int ii = 0; ii < 32; ++ii) {
            const int gi = half + 2 * ii;
            const float a = fmaf(acc[ii], cr[gi], bc);
            acc[ii] = a; s1 += a; s2 += a * a;
        }
    }
    red[t] = s1; __syncthreads();
    if (t < 128) ml[c] = (red[t] + red[t + 128]) * (1.0f / NG);
    __syncthreads();
    red[t] = s2; __syncthreads();
    if (t < 128) {
        const float ms = (red[t] + red[t + 128]) * (1.0f / NG);
        const float mm = ml[c];
        il[c] = rsqrtf(ms - mm * mm + EPSV);
    }
    __syncthreads();
    {
        const float mm = ml[c], iv = il[c], gg = Ag1[c], bb = Ab1[c];
#pragma unroll
        for (int ii = 0; ii < 32; ++ii) {
            const int gi = half + 2 * ii;
            Z[gi * FD + c] = fmaxf((acc[ii] - mm) * iv * gg + bb, 0.f);
        }
    }
    __syncthreads();
    // ---- layer 2 dot: acc[ii] = Z[gi] . A2w[c] (Z reads are LDS broadcast) --
#pragma unroll
    for (int ii = 0; ii < 32; ++ii) acc[ii] = 0.f;
#pragma unroll 1
    for (int kc = 0; kc < 4; ++kc) {
        float4 wr[8];
        const float4* wp = (const float4*)(A2w + c * FD + kc * 32);
#pragma unroll
        for (int i = 0; i < 8; ++i) wr[i] = wp[i];
#pragma unroll
        for (int ii = 0; ii < 32; ++ii) {
            const int gi = half + 2 * ii;
            const float4* pp = (const float4*)(&Z[gi * FD + kc * 32]);
            float d = 0.f;
#pragma unroll
            for (int i = 0; i < 8; ++i) {
                const float4 w4 = wr[i], p4 = pp[i];
                d += w4.x * p4.x + w4.y * p4.y + w4.z * p4.z + w4.w * p4.w;
            }
            acc[ii] += d;
        }
    }
    s1 = 0.f; s2 = 0.f;
    {
        const float bc = A2b[c];
#pragma unroll
        for (int ii = 0; ii < 32; ++ii) {
            const float a = acc[ii] + bc;
            acc[ii] = a; s1 += a; s2 += a * a;
        }
    }
    red[t] = s1; __syncthreads();
    if (t < 128) ml[c] = (red[t] + red[t + 128]) * (1.0f / NG);
    __syncthreads();
    red[t] = s2; __syncthreads();
    if (t < 128) {
        const float ms = (red[t] + red[t + 128]) * (1.0f / NG);
        const float mm = ml[c];
        il[c] = rsqrtf(ms - mm * mm + EPSV);
    }
    __syncthreads();
    {
        const float mm = ml[c], iv = il[c], gg = Ag2[c], bb = Ab2[c];
#pragma unroll
        for (int ii = 0; ii < 32; ++ii) {
            const int gi = half + 2 * ii;
            Z[gi * FD + c] = fmaxf((acc[ii] - mm) * iv * gg + bb, 0.f);
        }
    }
    __syncthreads();
    // ---- layer 3 + sigmoid ----
    for (int i = t; i < NG * NA; i += 256) {
        const int gi = i >> 4;
        const int a = i & 15;
        const float4* wp = (const float4*)(A3w + a * FD);
        const float4* pp = (const float4*)(&Z[gi * FD]);
        float d = A3b[a];
#pragma unroll 8
        for (int k4 = 0; k4 < 32; ++k4) {
            const float4 w4 = wp[k4];
            const float4 p4 = pp[k4];
            d += w4.x * p4.x + w4.y * p4.y + w4.z * p4.z + w4.w * p4.w;
        }
        out[i] = sigf(d);
    }
}

extern "C" void kernel_launch(void* const* d_in, const int* in_sizes, int n_in,
                              void* d_out, int out_size, void* d_ws, size_t ws_size,
                              hipStream_t stream)
{
    const float* x     = (const float*)d_in[0];
    const float* ea    = (const float*)d_in[1];
    const int*   ei    = (const int*)d_in[2];
    const int*   batch = (const int*)d_in[3];
    const float* W1  = (const float*)d_in[4];
    const float* b1  = (const float*)d_in[5];
    const float* We1 = (const float*)d_in[6];
    const float* be1 = (const float*)d_in[7];
    const float* g1  = (const float*)d_in[8];
    const float* bt1 = (const float*)d_in[9];
    const float* W2  = (const float*)d_in[10];
    const float* b2  = (const float*)d_in[11];
    const float* We2 = (const float*)d_in[12];
    const float* be2 = (const float*)d_in[13];
    const float* g2  = (const float*)d_in[14];
    const float* bt2 = (const float*)d_in[15];
    const float* A1w = (const float*)d_in[16];
    const float* A1b = (const float*)d_in[17];
    const float* Ag1 = (const float*)d_in[18];
    const float* Ab1 = (const float*)d_in[19];
    const float* A2w = (const float*)d_in[20];
    const float* A2b = (const float*)d_in[21];
    const float* Ag2 = (const float*)d_in[22];
    const float* Ab2 = (const float*)d_in[23];
    const float* A3w = (const float*)d_in[24];
    const float* A3b = (const float*)d_in[25];
    float* out = (float*)d_out;

    float* ws      = (float*)d_ws;
    float* xpa     = ws;                       // [NN*FD]
    float* hpre    = ws + (long)NN * FD;       // [NN*FD]
    float* stats   = ws + 2L * NN * FD;        // 512 + NG*FD floats
    float* colsum1 = stats;
    float* colsq1  = stats + 128;
    float* colsum2 = stats + 256;
    float* colsq2  = stats + 384;
    float* pooled  = stats + 512;
    int*   ibase   = (int*)(stats + 512 + NG * FD);
    int2*  perm    = (int2*)ibase;             // [NE]
    int*   off     = ibase + 2 * NE;           // [NN+2]
    int*   cur     = off + NN + 2;             // [NN]
    int*   chunk   = cur + NN;                 // [256]

    hipMemsetAsync(off, 0, (NN + 2) * sizeof(int), stream);
    hipMemsetAsync(stats, 0, (512 + NG * FD) * sizeof(float), stream);

    // CSR build (once; shared by both stages)
    count_kernel<<<NE / 256, 256, 0, stream>>>(ei, off);
    scan1_kernel<<<NCH, 256, 0, stream>>>(off, chunk);
    scan2_kernel<<<1, 256, 0, stream>>>(chunk);
    scan3_kernel<<<NCH, 256, 0, stream>>>(off, cur, chunk);
    scatter_kernel<<<NE / 256, 256, 0, stream>>>(ei, cur, perm);

    // stage 1
    edge_agg_kernel<false><<<NN / 4, 256, 0, stream>>>(
        x, nullptr, nullptr, nullptr, nullptr, ea, off, perm, We1, be1, xpa);
    node_kernel<<<512, 256, 0, stream>>>(xpa, W1, b1, hpre, colsum1, colsq1);

    // stage 2 (BN+relu of stage 1 fused into the gather)
    edge_agg_kernel<true><<<NN / 4, 256, 0, stream>>>(
        hpre, colsum1, colsq1, g1, bt1, ea, off, perm, We2, be2, xpa);
    node_kernel<<<512, 256, 0, stream>>>(xpa, W2, b2, hpre, colsum2, colsq2);

    norm_pool_kernel<<<(NN + 127) / 128, 256, 0, stream>>>(
        hpre, colsum2, colsq2, g2, bt2, batch, pooled);
    mlp_kernel<<<1, 256, 0, stream>>>(pooled, batch, A1w, A1b, Ag1, Ab1,
                                      A2w, A2b, Ag2, Ab2, A3w, A3b, out);
}

// Round 5
// 1007.385 us; speedup vs baseline: 1.8781x; 1.1291x over previous
//
#include <hip/hip_runtime.h>
#include <math.h>

#define NN 50000
#define NE 800000
#define FD 128
#define EDD 32
#define NG 64
#define NA 16
#define EPSV 1e-5f
#define NCH 196            // ceil(NN/256) chunks for the scan
#define EC 32              // edges staged per chunk per wave
#define NPW 4              // nodes per wave

typedef float v2f __attribute__((ext_vector_type(2)));

__device__ __forceinline__ float sigf(float v) { return 1.0f / (1.0f + __expf(-v)); }
__device__ __forceinline__ v2f mk2(float a, float b) { v2f r; r.x = a; r.y = b; return r; }
__device__ __forceinline__ v2f pfma(v2f a, v2f b, v2f c) { return __builtin_elementwise_fma(a, b, c); }
__device__ __forceinline__ v2f pmax0(v2f a) { return __builtin_elementwise_max(a, mk2(0.f, 0.f)); }

// ============ counting sort of edges by dst (CSR build) ====================
__global__ __launch_bounds__(256) void count_kernel(const int* __restrict__ ei,
                                                    int* __restrict__ off)
{
    const int e = blockIdx.x * 256 + threadIdx.x;
    atomicAdd(&off[ei[NE + e]], 1);
}

__global__ __launch_bounds__(256) void scan1_kernel(const int* __restrict__ off,
                                                    int* __restrict__ chunk)
{
    __shared__ int red[256];
    const int i = blockIdx.x * 256 + threadIdx.x;
    red[threadIdx.x] = (i < NN) ? off[i] : 0;
    __syncthreads();
    for (int o = 128; o > 0; o >>= 1) {
        if (threadIdx.x < o) red[threadIdx.x] += red[threadIdx.x + o];
        __syncthreads();
    }
    if (threadIdx.x == 0) chunk[blockIdx.x] = red[0];
}

__global__ __launch_bounds__(256) void scan2_kernel(int* __restrict__ chunk)
{
    __shared__ int sh[256];
    const int t = threadIdx.x;
    const int v = (t < NCH) ? chunk[t] : 0;
    sh[t] = v;
    __syncthreads();
    for (int o = 1; o < 256; o <<= 1) {
        int x = (t >= o) ? sh[t - o] : 0;
        __syncthreads();
        sh[t] += x;
        __syncthreads();
    }
    if (t < NCH) chunk[t] = sh[t] - v;
}

__global__ __launch_bounds__(256) void scan3_kernel(int* __restrict__ off,
                                                    int* __restrict__ cur,
                                                    const int* __restrict__ chunk)
{
    __shared__ int sh[256];
    const int t = threadIdx.x;
    const int i = blockIdx.x * 256 + t;
    const int v = (i < NN) ? off[i] : 0;
    sh[t] = v;
    __syncthreads();
    for (int o = 1; o < 256; o <<= 1) {
        int x = (t >= o) ? sh[t - o] : 0;
        __syncthreads();
        sh[t] += x;
        __syncthreads();
    }
    const int ex = sh[t] - v + chunk[blockIdx.x];
    if (i < NN) { off[i] = ex; cur[i] = ex; }
    if (i == 0) off[NN] = NE;
}

__global__ __launch_bounds__(256) void scatter_kernel(const int* __restrict__ ei,
                                                      int* __restrict__ cur,
                                                      int2* __restrict__ perm)
{
    const int e = blockIdx.x * 256 + threadIdx.x;
    const int src = ei[e];
    const int dst = ei[NE + e];
    const int pos = atomicAdd(&cur[dst], 1);
    perm[pos] = make_int2(src, e);
}

// ============ gather edge stage: one wave per 4 consecutive nodes ==========
// xpa[n] = tr(x[n]) + sum_{e: dst=n} relu(tr(x[src_e]) + ea_e @ We^T + be)
// Wave walks its contiguous CSR edge range [off[n0],off[n0+4]) in 32-edge
// chunks; packed v2f math (2 channels/lane); register-double-buffered LDS
// staging; wave-uniform node-boundary flushes; no barriers, no atomics.
template<bool TR>
__global__ __launch_bounds__(256) void edge_agg_kernel(
    const float* __restrict__ xin, const float* __restrict__ cs,
    const float* __restrict__ cq, const float* __restrict__ ga,
    const float* __restrict__ bb, const float* __restrict__ eattr,
    const int* __restrict__ off, const int2* __restrict__ perm,
    const float* __restrict__ We, const float* __restrict__ be,
    float* __restrict__ xpa)
{
    __shared__ float ea_s[4][EC * EDD];   // 16 KB, per-wave private
    __shared__ int   src_s[4][EC];
    const int t = threadIdx.x;
    const int w = t >> 6;
    const int l = t & 63;
    const int n0 = (blockIdx.x * 4 + w) * NPW;

    // packed weights: wk[k] = {We[l][k], We[l+64][k]}
    v2f wk[EDD];
    {
        const float4* a  = (const float4*)(We + l * EDD);
        const float4* b2 = (const float4*)(We + (l + 64) * EDD);
#pragma unroll
        for (int i = 0; i < 8; ++i) {
            const float4 va = a[i], vb = b2[i];
            wk[4*i+0] = mk2(va.x, vb.x);
            wk[4*i+1] = mk2(va.y, vb.y);
            wk[4*i+2] = mk2(va.z, vb.z);
            wk[4*i+3] = mk2(va.w, vb.w);
        }
    }
    const v2f bev = mk2(be[l], be[l + 64]);
    v2f Av = mk2(1.f, 1.f), Bv = mk2(0.f, 0.f);
    if (TR) {
        const float invN = 1.0f / (float)NN;
        const float m0 = cs[l] * invN;
        const float i0 = rsqrtf(cq[l] * invN - m0 * m0 + EPSV);
        const float m1 = cs[l + 64] * invN;
        const float i1 = rsqrtf(cq[l + 64] * invN - m1 * m1 + EPSV);
        Av = mk2(i0 * ga[l], i1 * ga[l + 64]);
        Bv = mk2(bb[l] - m0 * Av.x, bb[l + 64] - m1 * Av.y);
    }
    const int o0 = off[n0];
    const int o1 = off[n0 + 1];
    const int o2 = off[n0 + 2];
    const int o3 = off[n0 + 3];
    const int o4 = off[n0 + 4];

    // preload + transform all 4 node-init rows
    auto ldx = [&](int node) -> v2f {
        v2f v = mk2(xin[(long)node * FD + l], xin[(long)node * FD + 64 + l]);
        return TR ? pmax0(pfma(v, Av, Bv)) : v;
    };
    const v2f ni0 = ldx(n0), ni1 = ldx(n0 + 1), ni2 = ldx(n0 + 2), ni3 = ldx(n0 + 3);

    const int total = o4 - o0;
    const int nchk = (total + EC - 1) / EC;
    const int p   = l & 7;
    const int jb0 = l >> 3;

    float4 pf[4];
    int    psrc = 0;
    auto prefetch = [&](int ch) {
        const int base = o0 + ch * EC;
        const int n = min(EC, o4 - base);
#pragma unroll
        for (int r = 0; r < 4; ++r) {
            const int jj = jb0 + 8 * r;
            pf[r] = (jj < n)
                ? *(const float4*)(eattr + (long)perm[base + jj].y * EDD + p * 4)
                : make_float4(0.f, 0.f, 0.f, 0.f);
        }
        if (l < EC && l < n) psrc = perm[base + l].x;
    };

    int cur = n0;
    int nxt_end = o1;
    v2f acc = ni0;
    int eidx = o0;

    if (nchk > 0) prefetch(0);
    for (int ch = 0; ch < nchk; ++ch) {
        // commit staged regs to this wave's LDS region
#pragma unroll
        for (int r = 0; r < 4; ++r)
            *(float4*)(&ea_s[w][(jb0 + 8 * r) * EDD + p * 4]) = pf[r];
        if (l < EC) src_s[w][l] = psrc;
        const int base = o0 + ch * EC;
        const int n = min(EC, o4 - base);
        if (ch + 1 < nchk) prefetch(ch + 1);   // overlap next chunk's global loads

        // x-row pipeline, groups of 4 edges
        v2f cx[4];
#pragma unroll
        for (int q = 0; q < 4; ++q) {
            if (q < n) {
                const int s = src_s[w][q];
                cx[q] = mk2(xin[(long)s * FD + l], xin[(long)s * FD + 64 + l]);
            } else cx[q] = mk2(0.f, 0.f);
        }
        const int ng = (n + 3) >> 2;
        for (int g = 0; g < ng; ++g) {
            const int jg = g * 4;
            v2f nx[4];
#pragma unroll
            for (int q = 0; q < 4; ++q) {
                const int j = jg + 4 + q;
                if (j < n) {
                    const int s = src_s[w][j];
                    nx[q] = mk2(xin[(long)s * FD + l], xin[(long)s * FD + 64 + l]);
                } else nx[q] = mk2(0.f, 0.f);
            }
#pragma unroll
            for (int q = 0; q < 4; ++q) {
                const int j = jg + q;
                if (j < n) {
                    // wave-uniform node-boundary flush
                    while (eidx == nxt_end) {
                        xpa[(long)cur * FD + l]      = acc.x;
                        xpa[(long)cur * FD + 64 + l] = acc.y;
                        ++cur;
                        acc     = (cur == n0 + 1) ? ni1 : (cur == n0 + 2) ? ni2 : ni3;
                        nxt_end = (cur == n0 + 1) ? o2  : (cur == n0 + 2) ? o3  : o4;
                    }
                    const float4* ev = (const float4*)(&ea_s[w][j * EDD]);
                    v2f ma = bev, mb = mk2(0.f, 0.f);
#pragma unroll
                    for (int k = 0; k < 8; ++k) {
                        const float4 v = ev[k];
                        ma = pfma(mk2(v.x, v.x), wk[4*k+0], ma);
                        mb = pfma(mk2(v.y, v.y), wk[4*k+1], mb);
                        ma = pfma(mk2(v.z, v.z), wk[4*k+2], ma);
                        mb = pfma(mk2(v.w, v.w), wk[4*k+3], mb);
                    }
                    const v2f tx = TR ? pmax0(pfma(cx[q], Av, Bv)) : cx[q];
                    acc += pmax0(ma + mb + tx);
                    ++eidx;
                }
            }
#pragma unroll
            for (int q = 0; q < 4; ++q) cx[q] = nx[q];
        }
    }
    // final flush: current node + trailing (empty) nodes
    for (;;) {
        xpa[(long)cur * FD + l]      = acc.x;
        xpa[(long)cur * FD + 64 + l] = acc.y;
        if (cur == n0 + 3) break;
        ++cur;
        acc = (cur == n0 + 1) ? ni1 : (cur == n0 + 2) ? ni2 : ni3;
    }
}

// ============ node GEMM: hpre = xpa @ W^T + b, fused BN column stats =======
__global__ __launch_bounds__(256) void node_kernel(
    const float* __restrict__ xpa, const float* __restrict__ W,
    const float* __restrict__ b, float* __restrict__ hpre,
    float* __restrict__ colsum, float* __restrict__ colsq)
{
    __shared__ float rowJ[8 * 132];
    __shared__ float red[256];
    const int t = threadIdx.x;
    const int c = t & 127;
    const int half = t >> 7;
    const int js = t & 7;
    const int kk = t >> 3;
    const float bc = b[c];
    float4 wr[32];
    {
        const float4* wp = (const float4*)(W + c * FD);
#pragma unroll
        for (int i = 0; i < 32; ++i) wr[i] = wp[i];
    }
    float s1 = 0.0f, s2 = 0.0f;
    const int stride = gridDim.x * 8;
    const int iters = (NN + stride - 1) / stride;
    for (int it = 0; it < iters; ++it) {
        const int r0 = (blockIdx.x + it * gridDim.x) * 8;
        __syncthreads();
        {
            const int r = r0 + js;
            float4 v = make_float4(0.f, 0.f, 0.f, 0.f);
            if (r < NN) v = *(const float4*)(xpa + (long)r * FD + kk * 4);
            *(float4*)(&rowJ[js * 132 + kk * 4]) = v;
        }
        __syncthreads();
        float a0 = 0.f, a1 = 0.f, a2 = 0.f, a3 = 0.f;
        const int jb = half * 4;
#pragma unroll
        for (int k4 = 0; k4 < 32; ++k4) {
            const float4 w4 = wr[k4];
            const float4 r0v = *(const float4*)(&rowJ[(jb + 0) * 132 + k4 * 4]);
            const float4 r1v = *(const float4*)(&rowJ[(jb + 1) * 132 + k4 * 4]);
            const float4 r2v = *(const float4*)(&rowJ[(jb + 2) * 132 + k4 * 4]);
            const float4 r3v = *(const float4*)(&rowJ[(jb + 3) * 132 + k4 * 4]);
            a0 += w4.x * r0v.x + w4.y * r0v.y + w4.z * r0v.z + w4.w * r0v.w;
            a1 += w4.x * r1v.x + w4.y * r1v.y + w4.z * r1v.z + w4.w * r1v.w;
            a2 += w4.x * r2v.x + w4.y * r2v.y + w4.z * r2v.z + w4.w * r2v.w;
            a3 += w4.x * r3v.x + w4.y * r3v.y + w4.z * r3v.z + w4.w * r3v.w;
        }
        const float vals[4] = { a0 + bc, a1 + bc, a2 + bc, a3 + bc };
#pragma unroll
        for (int j2 = 0; j2 < 4; ++j2) {
            const int rr = r0 + jb + j2;
            if (rr < NN) {
                hpre[(long)rr * FD + c] = vals[j2];
                s1 += vals[j2];
                s2 += vals[j2] * vals[j2];
            }
        }
    }
    red[t] = s1;
    __syncthreads();
    float S1 = 0.f;
    if (t < 128) S1 = red[t] + red[t + 128];
    __syncthreads();
    red[t] = s2;
    __syncthreads();
    if (t < 128) {
        const float S2 = red[t] + red[t + 128];
        atomicAdd(&colsum[c], S1);
        atomicAdd(&colsq[c], S2);
    }
}

// ============ BN + relu + sigmoid + per-graph pooled sums (layer 2) ========
__global__ __launch_bounds__(256) void norm_pool_kernel(
    const float* __restrict__ hpre, const float* __restrict__ cs,
    const float* __restrict__ cq, const float* __restrict__ ga,
    const float* __restrict__ bb, const int* __restrict__ batch,
    float* __restrict__ pooled)
{
    __shared__ float pl[NG * FD];
    const int t = threadIdx.x;
    const int c = t & 127;
    const int half = t >> 7;
    const int r0 = blockIdx.x * 128;
    const int rend = min(r0 + 128, NN);
    const int gmin = batch[r0];
    const int gmax = batch[rend - 1];
    const int span = gmax - gmin + 1;
    for (int i = t; i < span * FD; i += 256) pl[i] = 0.f;
    __syncthreads();
    const float invN = 1.0f / (float)NN;
    const float m = cs[c] * invN;
    const float iv = rsqrtf(cq[c] * invN - m * m + EPSV);
    const float gg = ga[c];
    const float bt = bb[c];
    for (int ir = half; ir < 128; ir += 2) {
        const int r = r0 + ir;
        if (r >= rend) break;
        float v = (hpre[(long)r * FD + c] - m) * iv * gg + bt;
        v = sigf(fmaxf(v, 0.f));
        atomicAdd(&pl[(batch[r] - gmin) * FD + c], v);
    }
    __syncthreads();
    for (int i = t; i < span * FD; i += 256) atomicAdd(&pooled[gmin * FD + i], pl[i]);
}

__device__ __forceinline__ int lbound(const int* __restrict__ a, int n, int v)
{
    int lo = 0, hi = n;
    while (lo < hi) { const int mid = (lo + hi) >> 1; if (a[mid] < v) lo = mid + 1; else hi = mid; }
    return lo;
}

// ============ action MLP head, single block ================================
__global__ __launch_bounds__(256) void mlp_kernel(
    const float* __restrict__ pooled, const int* __restrict__ batch,
    const float* __restrict__ A1w, const float* __restrict__ A1b,
    const float* __restrict__ Ag1, const float* __restrict__ Ab1,
    const float* __restrict__ A2w, const float* __restrict__ A2b,
    const float* __restrict__ Ag2, const float* __restrict__ Ab2,
    const float* __restrict__ A3w, const float* __restrict__ A3b,
    float* __restrict__ out)
{
    __shared__ float Z[NG * FD];
    __shared__ float red[256];
    __shared__ float ml[128], il[128];
    __shared__ float cr[NG];
    const int t = threadIdx.x;
    const int c = t & 127;
    const int half = t >> 7;
    if (t < NG) {
        const int lo = lbound(batch, NN, t);
        const int hi = lbound(batch, NN, t + 1);
        cr[t] = 1.0f / fmaxf((float)(hi - lo), 1.0f);
    }
    float acc[32];
#pragma unroll
    for (int ii = 0; ii < 32; ++ii) acc[ii] = 0.f;
#pragma unroll 1
    for (int kc = 0; kc < 4; ++kc) {
        float4 wr[8];
        const float4* wp = (const float4*)(A1w + c * FD + kc * 32);
#pragma unroll
        for (int i = 0; i < 8; ++i) wr[i] = wp[i];
#pragma unroll
        for (int ii = 0; ii < 32; ++ii) {
            const int gi = half + 2 * ii;
            const float4* pp = (const float4*)(pooled + gi * FD + kc * 32);
            float d = 0.f;
#pragma unroll
            for (int i = 0; i < 8; ++i) {
                const float4 w4 = wr[i], p4 = pp[i];
                d += w4.x * p4.x + w4.y * p4.y + w4.z * p4.z + w4.w * p4.w;
            }
            acc[ii] += d;
        }
    }
    __syncthreads();
    float s1 = 0.f, s2 = 0.f;
    {
        const float bc = A1b[c];
#pragma unroll
        for (int ii = 0; ii < 32; ++ii) {
            const int gi = half + 2 * ii;
            const float a = fmaf(acc[ii], cr[gi], bc);
            acc[ii] = a; s1 += a; s2 += a * a;
        }
    }
    red[t] = s1; __syncthreads();
    if (t < 128) ml[c] = (red[t] + red[t + 128]) * (1.0f / NG);
    __syncthreads();
    red[t] = s2; __syncthreads();
    if (t < 128) {
        const float ms = (red[t] + red[t + 128]) * (1.0f / NG);
        const float mm = ml[c];
        il[c] = rsqrtf(ms - mm * mm + EPSV);
    }
    __syncthreads();
    {
        const float mm = ml[c], iv = il[c], gg = Ag1[c], bb = Ab1[c];
#pragma unroll
        for (int ii = 0; ii < 32; ++ii) {
            const int gi = half + 2 * ii;
            Z[gi * FD + c] = fmaxf((acc[ii] - mm) * iv * gg + bb, 0.f);
        }
    }
    __syncthreads();
#pragma unroll
    for (int ii = 0; ii < 32; ++ii) acc[ii] = 0.f;
#pragma unroll 1
    for (int kc = 0; kc < 4; ++kc) {
        float4 wr[8];
        const float4* wp = (const float4*)(A2w + c * FD + kc * 32);
#pragma unroll
        for (int i = 0; i < 8; ++i) wr[i] = wp[i];
#pragma unroll
        for (int ii = 0; ii < 32; ++ii) {
            const int gi = half + 2 * ii;
            const float4* pp = (const float4*)(&Z[gi * FD + kc * 32]);
            float d = 0.f;
#pragma unroll
            for (int i = 0; i < 8; ++i) {
                const float4 w4 = wr[i], p4 = pp[i];
                d += w4.x * p4.x + w4.y * p4.y + w4.z * p4.z + w4.w * p4.w;
            }
            acc[ii] += d;
        }
    }
    s1 = 0.f; s2 = 0.f;
    {
        const float bc = A2b[c];
#pragma unroll
        for (int ii = 0; ii < 32; ++ii) {
            const float a = acc[ii] + bc;
            acc[ii] = a; s1 += a; s2 += a * a;
        }
    }
    red[t] = s1; __syncthreads();
    if (t < 128) ml[c] = (red[t] + red[t + 128]) * (1.0f / NG);
    __syncthreads();
    red[t] = s2; __syncthreads();
    if (t < 128) {
        const float ms = (red[t] + red[t + 128]) * (1.0f / NG);
        const float mm = ml[c];
        il[c] = rsqrtf(ms - mm * mm + EPSV);
    }
    __syncthreads();
    {
        const float mm = ml[c], iv = il[c], gg = Ag2[c], bb = Ab2[c];
#pragma unroll
        for (int ii = 0; ii < 32; ++ii) {
            const int gi = half + 2 * ii;
            Z[gi * FD + c] = fmaxf((acc[ii] - mm) * iv * gg + bb, 0.f);
        }
    }
    __syncthreads();
    for (int i = t; i < NG * NA; i += 256) {
        const int gi = i >> 4;
        const int a = i & 15;
        const float4* wp = (const float4*)(A3w + a * FD);
        const float4* pp = (const float4*)(&Z[gi * FD]);
        float d = A3b[a];
#pragma unroll 8
        for (int k4 = 0; k4 < 32; ++k4) {
            const float4 w4 = wp[k4];
            const float4 p4 = pp[k4];
            d += w4.x * p4.x + w4.y * p4.y + w4.z * p4.z + w4.w * p4.w;
        }
        out[i] = sigf(d);
    }
}

extern "C" void kernel_launch(void* const* d_in, const int* in_sizes, int n_in,
                              void* d_out, int out_size, void* d_ws, size_t ws_size,
                              hipStream_t stream)
{
    const float* x     = (const float*)d_in[0];
    const float* ea    = (const float*)d_in[1];
    const int*   ei    = (const int*)d_in[2];
    const int*   batch = (const int*)d_in[3];
    const float* W1  = (const float*)d_in[4];
    const float* b1  = (const float*)d_in[5];
    const float* We1 = (const float*)d_in[6];
    const float* be1 = (const float*)d_in[7];
    const float* g1  = (const float*)d_in[8];
    const float* bt1 = (const float*)d_in[9];
    const float* W2  = (const float*)d_in[10];
    const float* b2  = (const float*)d_in[11];
    const float* We2 = (const float*)d_in[12];
    const float* be2 = (const float*)d_in[13];
    const float* g2  = (const float*)d_in[14];
    const float* bt2 = (const float*)d_in[15];
    const float* A1w = (const float*)d_in[16];
    const float* A1b = (const float*)d_in[17];
    const float* Ag1 = (const float*)d_in[18];
    const float* Ab1 = (const float*)d_in[19];
    const float* A2w = (const float*)d_in[20];
    const float* A2b = (const float*)d_in[21];
    const float* Ag2 = (const float*)d_in[22];
    const float* Ab2 = (const float*)d_in[23];
    const float* A3w = (const float*)d_in[24];
    const float* A3b = (const float*)d_in[25];
    float* out = (float*)d_out;

    float* ws      = (float*)d_ws;
    float* xpa     = ws;                       // [NN*FD]
    float* hpre    = ws + (long)NN * FD;       // [NN*FD]
    float* stats   = ws + 2L * NN * FD;        // 512 + NG*FD floats
    float* colsum1 = stats;
    float* colsq1  = stats + 128;
    float* colsum2 = stats + 256;
    float* colsq2  = stats + 384;
    float* pooled  = stats + 512;
    int*   ibase   = (int*)(stats + 512 + NG * FD);
    int2*  perm    = (int2*)ibase;             // [NE]
    int*   off     = ibase + 2 * NE;           // [NN+2]
    int*   cur     = off + NN + 2;             // [NN]
    int*   chunk   = cur + NN;                 // [256]

    hipMemsetAsync(off, 0, (NN + 2) * sizeof(int), stream);
    hipMemsetAsync(stats, 0, (512 + NG * FD) * sizeof(float), stream);

    // CSR build (once; shared by both stages)
    count_kernel<<<NE / 256, 256, 0, stream>>>(ei, off);
    scan1_kernel<<<NCH, 256, 0, stream>>>(off, chunk);
    scan2_kernel<<<1, 256, 0, stream>>>(chunk);
    scan3_kernel<<<NCH, 256, 0, stream>>>(off, cur, chunk);
    scatter_kernel<<<NE / 256, 256, 0, stream>>>(ei, cur, perm);

    // stage 1
    edge_agg_kernel<false><<<NN / (4 * NPW), 256, 0, stream>>>(
        x, nullptr, nullptr, nullptr, nullptr, ea, off, perm, We1, be1, xpa);
    node_kernel<<<512, 256, 0, stream>>>(xpa, W1, b1, hpre, colsum1, colsq1);

    // stage 2 (BN+relu of stage 1 fused into the gather)
    edge_agg_kernel<true><<<NN / (4 * NPW), 256, 0, stream>>>(
        hpre, colsum1, colsq1, g1, bt1, ea, off, perm, We2, be2, xpa);
    node_kernel<<<512, 256, 0, stream>>>(xpa, W2, b2, hpre, colsum2, colsq2);

    norm_pool_kernel<<<(NN + 127) / 128, 256, 0, stream>>>(
        hpre, colsum2, colsq2, g2, bt2, batch, pooled);
    mlp_kernel<<<1, 256, 0, stream>>>(pooled, batch, A1w, A1b, Ag1, Ab1,
                                      A2w, A2b, Ag2, Ab2, A3w, A3b, out);
}

// Round 6
// 1000.298 us; speedup vs baseline: 1.8915x; 1.0071x over previous
//
#include <hip/hip_runtime.h>
#include <math.h>

#define NN 50000
#define NE 800000
#define FD 128
#define EDD 32
#define NG 64
#define NA 16
#define EPSV 1e-5f
#define NCH 196            // ceil(NN/256) chunks for the scan
#define EC 32              // edges staged per chunk per wave
#define NPW 4              // nodes per wave

typedef float v2f __attribute__((ext_vector_type(2)));

__device__ __forceinline__ float sigf(float v) { return 1.0f / (1.0f + __expf(-v)); }
__device__ __forceinline__ v2f mk2(float a, float b) { v2f r; r.x = a; r.y = b; return r; }
__device__ __forceinline__ v2f pfma(v2f a, v2f b, v2f c) { return __builtin_elementwise_fma(a, b, c); }
__device__ __forceinline__ v2f pmax0(v2f a) { return __builtin_elementwise_max(a, mk2(0.f, 0.f)); }

// ============ counting sort of edges by dst (CSR build) ====================
__global__ __launch_bounds__(256) void count_kernel(const int* __restrict__ ei,
                                                    int* __restrict__ off)
{
    const int e = blockIdx.x * 256 + threadIdx.x;
    atomicAdd(&off[ei[NE + e]], 1);
}

__global__ __launch_bounds__(256) void scan1_kernel(const int* __restrict__ off,
                                                    int* __restrict__ chunk)
{
    __shared__ int red[256];
    const int i = blockIdx.x * 256 + threadIdx.x;
    red[threadIdx.x] = (i < NN) ? off[i] : 0;
    __syncthreads();
    for (int o = 128; o > 0; o >>= 1) {
        if (threadIdx.x < o) red[threadIdx.x] += red[threadIdx.x + o];
        __syncthreads();
    }
    if (threadIdx.x == 0) chunk[blockIdx.x] = red[0];
}

__global__ __launch_bounds__(256) void scan2_kernel(int* __restrict__ chunk)
{
    __shared__ int sh[256];
    const int t = threadIdx.x;
    const int v = (t < NCH) ? chunk[t] : 0;
    sh[t] = v;
    __syncthreads();
    for (int o = 1; o < 256; o <<= 1) {
        int x = (t >= o) ? sh[t - o] : 0;
        __syncthreads();
        sh[t] += x;
        __syncthreads();
    }
    if (t < NCH) chunk[t] = sh[t] - v;
}

__global__ __launch_bounds__(256) void scan3_kernel(int* __restrict__ off,
                                                    int* __restrict__ cur,
                                                    const int* __restrict__ chunk)
{
    __shared__ int sh[256];
    const int t = threadIdx.x;
    const int i = blockIdx.x * 256 + t;
    const int v = (i < NN) ? off[i] : 0;
    sh[t] = v;
    __syncthreads();
    for (int o = 1; o < 256; o <<= 1) {
        int x = (t >= o) ? sh[t - o] : 0;
        __syncthreads();
        sh[t] += x;
        __syncthreads();
    }
    const int ex = sh[t] - v + chunk[blockIdx.x];
    if (i < NN) { off[i] = ex; cur[i] = ex; }
    if (i == 0) off[NN] = NE;
}

__global__ __launch_bounds__(256) void scatter_kernel(const int* __restrict__ ei,
                                                      int* __restrict__ cur,
                                                      int2* __restrict__ perm)
{
    const int e = blockIdx.x * 256 + threadIdx.x;
    const int src = ei[e];
    const int dst = ei[NE + e];
    const int pos = atomicAdd(&cur[dst], 1);
    perm[pos] = make_int2(src, e);
}

// ============ gather edge stage: one wave per 4 consecutive nodes ==========
// 128-thread blocks (2 waves) -> ~8.5 KB LDS/block for higher occupancy.
template<bool TR>
__global__ __launch_bounds__(128) void edge_agg_kernel(
    const float* __restrict__ xin, const float* __restrict__ cs,
    const float* __restrict__ cq, const float* __restrict__ ga,
    const float* __restrict__ bb, const float* __restrict__ eattr,
    const int* __restrict__ off, const int2* __restrict__ perm,
    const float* __restrict__ We, const float* __restrict__ be,
    float* __restrict__ xpa)
{
    __shared__ float ea_s[2][EC * EDD];   // 8 KB, per-wave private
    __shared__ int   src_s[2][EC];
    const int t = threadIdx.x;
    const int w = t >> 6;
    const int l = t & 63;
    const int n0 = (blockIdx.x * 2 + w) * NPW;

    // packed weights: wk[k] = {We[l][k], We[l+64][k]}
    v2f wk[EDD];
    {
        const float4* a  = (const float4*)(We + l * EDD);
        const float4* b2 = (const float4*)(We + (l + 64) * EDD);
#pragma unroll
        for (int i = 0; i < 8; ++i) {
            const float4 va = a[i], vb = b2[i];
            wk[4*i+0] = mk2(va.x, vb.x);
            wk[4*i+1] = mk2(va.y, vb.y);
            wk[4*i+2] = mk2(va.z, vb.z);
            wk[4*i+3] = mk2(va.w, vb.w);
        }
    }
    const v2f bev = mk2(be[l], be[l + 64]);
    v2f Av = mk2(1.f, 1.f), Bv = mk2(0.f, 0.f);
    if (TR) {
        const float invN = 1.0f / (float)NN;
        const float m0 = cs[l] * invN;
        const float i0 = rsqrtf(cq[l] * invN - m0 * m0 + EPSV);
        const float m1 = cs[l + 64] * invN;
        const float i1 = rsqrtf(cq[l + 64] * invN - m1 * m1 + EPSV);
        Av = mk2(i0 * ga[l], i1 * ga[l + 64]);
        Bv = mk2(bb[l] - m0 * Av.x, bb[l + 64] - m1 * Av.y);
    }
    const int o0 = off[n0];
    const int o1 = off[n0 + 1];
    const int o2 = off[n0 + 2];
    const int o3 = off[n0 + 3];
    const int o4 = off[n0 + 4];

    auto ldx = [&](int node) -> v2f {
        v2f v = mk2(xin[(long)node * FD + l], xin[(long)node * FD + 64 + l]);
        return TR ? pmax0(pfma(v, Av, Bv)) : v;
    };
    const v2f ni0 = ldx(n0), ni1 = ldx(n0 + 1), ni2 = ldx(n0 + 2), ni3 = ldx(n0 + 3);

    const int total = o4 - o0;
    const int nchk = (total + EC - 1) / EC;
    const int p   = l & 7;
    const int jb0 = l >> 3;

    float4 pf[4];
    int    psrc = 0;
    auto prefetch = [&](int ch) {
        const int base = o0 + ch * EC;
        const int n = min(EC, o4 - base);
#pragma unroll
        for (int r = 0; r < 4; ++r) {
            const int jj = jb0 + 8 * r;
            pf[r] = (jj < n)
                ? *(const float4*)(eattr + (long)perm[base + jj].y * EDD + p * 4)
                : make_float4(0.f, 0.f, 0.f, 0.f);
        }
        if (l < EC && l < n) psrc = perm[base + l].x;
    };

    int cur = n0;
    int nxt_end = o1;
    v2f acc = ni0;
    int eidx = o0;

    if (nchk > 0) prefetch(0);
    for (int ch = 0; ch < nchk; ++ch) {
#pragma unroll
        for (int r = 0; r < 4; ++r)
            *(float4*)(&ea_s[w][(jb0 + 8 * r) * EDD + p * 4]) = pf[r];
        if (l < EC) src_s[w][l] = psrc;
        const int base = o0 + ch * EC;
        const int n = min(EC, o4 - base);
        if (ch + 1 < nchk) prefetch(ch + 1);

        v2f cx[4];
#pragma unroll
        for (int q = 0; q < 4; ++q) {
            if (q < n) {
                const int s = src_s[w][q];
                cx[q] = mk2(xin[(long)s * FD + l], xin[(long)s * FD + 64 + l]);
            } else cx[q] = mk2(0.f, 0.f);
        }
        const int ng = (n + 3) >> 2;
        for (int g = 0; g < ng; ++g) {
            const int jg = g * 4;
            v2f nx[4];
#pragma unroll
            for (int q = 0; q < 4; ++q) {
                const int j = jg + 4 + q;
                if (j < n) {
                    const int s = src_s[w][j];
                    nx[q] = mk2(xin[(long)s * FD + l], xin[(long)s * FD + 64 + l]);
                } else nx[q] = mk2(0.f, 0.f);
            }
#pragma unroll
            for (int q = 0; q < 4; ++q) {
                const int j = jg + q;
                if (j < n) {
                    while (eidx == nxt_end) {
                        xpa[(long)cur * FD + l]      = acc.x;
                        xpa[(long)cur * FD + 64 + l] = acc.y;
                        ++cur;
                        acc     = (cur == n0 + 1) ? ni1 : (cur == n0 + 2) ? ni2 : ni3;
                        nxt_end = (cur == n0 + 1) ? o2  : (cur == n0 + 2) ? o3  : o4;
                    }
                    const float4* ev = (const float4*)(&ea_s[w][j * EDD]);
                    v2f ma = bev, mb = mk2(0.f, 0.f);
#pragma unroll
                    for (int k = 0; k < 8; ++k) {
                        const float4 v = ev[k];
                        ma = pfma(mk2(v.x, v.x), wk[4*k+0], ma);
                        mb = pfma(mk2(v.y, v.y), wk[4*k+1], mb);
                        ma = pfma(mk2(v.z, v.z), wk[4*k+2], ma);
                        mb = pfma(mk2(v.w, v.w), wk[4*k+3], mb);
                    }
                    const v2f tx = TR ? pmax0(pfma(cx[q], Av, Bv)) : cx[q];
                    acc += pmax0(ma + mb + tx);
                    ++eidx;
                }
            }
#pragma unroll
            for (int q = 0; q < 4; ++q) cx[q] = nx[q];
        }
    }
    for (;;) {
        xpa[(long)cur * FD + l]      = acc.x;
        xpa[(long)cur * FD + 64 + l] = acc.y;
        if (cur == n0 + 3) break;
        ++cur;
        acc = (cur == n0 + 1) ? ni1 : (cur == n0 + 2) ? ni2 : ni3;
    }
}

// ============ node GEMM: hpre = xpa @ W^T + b, fused BN column stats =======
// W row per thread in registers; rows read as wave-uniform (broadcast) loads,
// two rows in flight, 4 accumulators each. No LDS in the hot loop.
__global__ __launch_bounds__(256) void node_kernel(
    const float* __restrict__ xpa, const float* __restrict__ W,
    const float* __restrict__ b, float* __restrict__ hpre,
    float* __restrict__ colsum, float* __restrict__ colsq)
{
    __shared__ float red[256];
    const int t = threadIdx.x;
    const int c = t & 127;
    const int rp = t >> 7;
    const float bc = b[c];
    float wreg[FD];
    {
        const float4* wp = (const float4*)(W + c * FD);
#pragma unroll
        for (int i = 0; i < 32; ++i) {
            const float4 v = wp[i];
            wreg[4*i+0]=v.x; wreg[4*i+1]=v.y; wreg[4*i+2]=v.z; wreg[4*i+3]=v.w;
        }
    }
    float s1 = 0.f, s2 = 0.f;
    const int G = gridDim.x * 2;
    for (int r = blockIdx.x * 2 + rp; r < NN; r += 2 * G) {
        const int r1 = __builtin_amdgcn_readfirstlane(r);
        const int r2 = r1 + G;
        const float* row1 = xpa + (long)r1 * FD;
        if (r2 < NN) {
            const float* row2 = xpa + (long)r2 * FD;
            float a0=bc,a1=0.f,a2=0.f,a3=0.f, d0=bc,d1=0.f,d2=0.f,d3=0.f;
#pragma unroll
            for (int k = 0; k < FD; k += 4) {
                const float4 u = *(const float4*)(row1 + k);
                const float4 v = *(const float4*)(row2 + k);
                a0 = fmaf(u.x, wreg[k+0], a0);
                a1 = fmaf(u.y, wreg[k+1], a1);
                a2 = fmaf(u.z, wreg[k+2], a2);
                a3 = fmaf(u.w, wreg[k+3], a3);
                d0 = fmaf(v.x, wreg[k+0], d0);
                d1 = fmaf(v.y, wreg[k+1], d1);
                d2 = fmaf(v.z, wreg[k+2], d2);
                d3 = fmaf(v.w, wreg[k+3], d3);
            }
            const float va = (a0 + a1) + (a2 + a3);
            const float vb = (d0 + d1) + (d2 + d3);
            hpre[(long)r1 * FD + c] = va;
            hpre[(long)r2 * FD + c] = vb;
            s1 += va + vb; s2 += va * va + vb * vb;
        } else {
            float a0=bc,a1=0.f,a2=0.f,a3=0.f;
#pragma unroll
            for (int k = 0; k < FD; k += 4) {
                const float4 u = *(const float4*)(row1 + k);
                a0 = fmaf(u.x, wreg[k+0], a0);
                a1 = fmaf(u.y, wreg[k+1], a1);
                a2 = fmaf(u.z, wreg[k+2], a2);
                a3 = fmaf(u.w, wreg[k+3], a3);
            }
            const float va = (a0 + a1) + (a2 + a3);
            hpre[(long)r1 * FD + c] = va;
            s1 += va; s2 += va * va;
        }
    }
    red[t] = s1;
    __syncthreads();
    float S1 = 0.f;
    if (t < 128) S1 = red[t] + red[t + 128];
    __syncthreads();
    red[t] = s2;
    __syncthreads();
    if (t < 128) {
        const float S2 = red[t] + red[t + 128];
        atomicAdd(&colsum[c], S1);
        atomicAdd(&colsq[c], S2);
    }
}

// ============ BN + relu + sigmoid + per-graph pooled sums (layer 2) ========
__global__ __launch_bounds__(256) void norm_pool_kernel(
    const float* __restrict__ hpre, const float* __restrict__ cs,
    const float* __restrict__ cq, const float* __restrict__ ga,
    const float* __restrict__ bb, const int* __restrict__ batch,
    float* __restrict__ pooled)
{
    __shared__ float pl[NG * FD];
    const int t = threadIdx.x;
    const int c = t & 127;
    const int half = t >> 7;
    const int r0 = blockIdx.x * 128;
    const int rend = min(r0 + 128, NN);
    const int gmin = batch[r0];
    const int gmax = batch[rend - 1];
    const int span = gmax - gmin + 1;
    for (int i = t; i < span * FD; i += 256) pl[i] = 0.f;
    __syncthreads();
    const float invN = 1.0f / (float)NN;
    const float m = cs[c] * invN;
    const float iv = rsqrtf(cq[c] * invN - m * m + EPSV);
    const float gg = ga[c];
    const float bt = bb[c];
    for (int ir = half; ir < 128; ir += 2) {
        const int r = r0 + ir;
        if (r >= rend) break;
        float v = (hpre[(long)r * FD + c] - m) * iv * gg + bt;
        v = sigf(fmaxf(v, 0.f));
        atomicAdd(&pl[(batch[r] - gmin) * FD + c], v);
    }
    __syncthreads();
    for (int i = t; i < span * FD; i += 256) atomicAdd(&pooled[gmin * FD + i], pl[i]);
}

__device__ __forceinline__ int lbound(const int* __restrict__ a, int n, int v)
{
    int lo = 0, hi = n;
    while (lo < hi) { const int mid = (lo + hi) >> 1; if (a[mid] < v) lo = mid + 1; else hi = mid; }
    return lo;
}

// ============ action MLP head, single block ================================
__global__ __launch_bounds__(256) void mlp_kernel(
    const float* __restrict__ pooled, const int* __restrict__ batch,
    const float* __restrict__ A1w, const float* __restrict__ A1b,
    const float* __restrict__ Ag1, const float* __restrict__ Ab1,
    const float* __restrict__ A2w, const float* __restrict__ A2b,
    const float* __restrict__ Ag2, const float* __restrict__ Ab2,
    const float* __restrict__ A3w, const float* __restrict__ A3b,
    float* __restrict__ out)
{
    __shared__ float Z[NG * FD];
    __shared__ float red[256];
    __shared__ float ml[128], il[128];
    __shared__ float cr[NG];
    const int t = threadIdx.x;
    const int c = t & 127;
    const int half = t >> 7;
    if (t < NG) {
        const int lo = lbound(batch, NN, t);
        const int hi = lbound(batch, NN, t + 1);
        cr[t] = 1.0f / fmaxf((float)(hi - lo), 1.0f);
    }
    float acc[32];
#pragma unroll
    for (int ii = 0; ii < 32; ++ii) acc[ii] = 0.f;
#pragma unroll 1
    for (int kc = 0; kc < 4; ++kc) {
        float4 wr[8];
        const float4* wp = (const float4*)(A1w + c * FD + kc * 32);
#pragma unroll
        for (int i = 0; i < 8; ++i) wr[i] = wp[i];
#pragma unroll
        for (int ii = 0; ii < 32; ++ii) {
            const int gi = half + 2 * ii;
            const float4* pp = (const float4*)(pooled + gi * FD + kc * 32);
            float d = 0.f;
#pragma unroll
            for (int i = 0; i < 8; ++i) {
                const float4 w4 = wr[i], p4 = pp[i];
                d += w4.x * p4.x + w4.y * p4.y + w4.z * p4.z + w4.w * p4.w;
            }
            acc[ii] += d;
        }
    }
    __syncthreads();
    float s1 = 0.f, s2 = 0.f;
    {
        const float bc = A1b[c];
#pragma unroll
        for (int ii = 0; ii < 32; ++ii) {
            const int gi = half + 2 * ii;
            const float a = fmaf(acc[ii], cr[gi], bc);
            acc[ii] = a; s1 += a; s2 += a * a;
        }
    }
    red[t] = s1; __syncthreads();
    if (t < 128) ml[c] = (red[t] + red[t + 128]) * (1.0f / NG);
    __syncthreads();
    red[t] = s2; __syncthreads();
    if (t < 128) {
        const float ms = (red[t] + red[t + 128]) * (1.0f / NG);
        const float mm = ml[c];
        il[c] = rsqrtf(ms - mm * mm + EPSV);
    }
    __syncthreads();
    {
        const float mm = ml[c], iv = il[c], gg = Ag1[c], bb = Ab1[c];
#pragma unroll
        for (int ii = 0; ii < 32; ++ii) {
            const int gi = half + 2 * ii;
            Z[gi * FD + c] = fmaxf((acc[ii] - mm) * iv * gg + bb, 0.f);
        }
    }
    __syncthreads();
#pragma unroll
    for (int ii = 0; ii < 32; ++ii) acc[ii] = 0.f;
#pragma unroll 1
    for (int kc = 0; kc < 4; ++kc) {
        float4 wr[8];
        const float4* wp = (const float4*)(A2w + c * FD + kc * 32);
#pragma unroll
        for (int i = 0; i < 8; ++i) wr[i] = wp[i];
#pragma unroll
        for (int ii = 0; ii < 32; ++ii) {
            const int gi = half + 2 * ii;
            const float4* pp = (const float4*)(&Z[gi * FD + kc * 32]);
            float d = 0.f;
#pragma unroll
            for (int i = 0; i < 8; ++i) {
                const float4 w4 = wr[i], p4 = pp[i];
                d += w4.x * p4.x + w4.y * p4.y + w4.z * p4.z + w4.w * p4.w;
            }
            acc[ii] += d;
        }
    }
    s1 = 0.f; s2 = 0.f;
    {
        const float bc = A2b[c];
#pragma unroll
        for (int ii = 0; ii < 32; ++ii) {
            const float a = acc[ii] + bc;
            acc[ii] = a; s1 += a; s2 += a * a;
        }
    }
    red[t] = s1; __syncthreads();
    if (t < 128) ml[c] = (red[t] + red[t + 128]) * (1.0f / NG);
    __syncthreads();
    red[t] = s2; __syncthreads();
    if (t < 128) {
        const float ms = (red[t] + red[t + 128]) * (1.0f / NG);
        const float mm = ml[c];
        il[c] = rsqrtf(ms - mm * mm + EPSV);
    }
    __syncthreads();
    {
        const float mm = ml[c], iv = il[c], gg = Ag2[c], bb = Ab2[c];
#pragma unroll
        for (int ii = 0; ii < 32; ++ii) {
            const int gi = half + 2 * ii;
            Z[gi * FD + c] = fmaxf((acc[ii] - mm) * iv * gg + bb, 0.f);
        }
    }
    __syncthreads();
    for (int i = t; i < NG * NA; i += 256) {
        const int gi = i >> 4;
        const int a = i & 15;
        const float4* wp = (const float4*)(A3w + a * FD);
        const float4* pp = (const float4*)(&Z[gi * FD]);
        float d = A3b[a];
#pragma unroll 8
        for (int k4 = 0; k4 < 32; ++k4) {
            const float4 w4 = wp[k4];
            const float4 p4 = pp[k4];
            d += w4.x * p4.x + w4.y * p4.y + w4.z * p4.z + w4.w * p4.w;
        }
        out[i] = sigf(d);
    }
}

extern "C" void kernel_launch(void* const* d_in, const int* in_sizes, int n_in,
                              void* d_out, int out_size, void* d_ws, size_t ws_size,
                              hipStream_t stream)
{
    const float* x     = (const float*)d_in[0];
    const float* ea    = (const float*)d_in[1];
    const int*   ei    = (const int*)d_in[2];
    const int*   batch = (const int*)d_in[3];
    const float* W1  = (const float*)d_in[4];
    const float* b1  = (const float*)d_in[5];
    const float* We1 = (const float*)d_in[6];
    const float* be1 = (const float*)d_in[7];
    const float* g1  = (const float*)d_in[8];
    const float* bt1 = (const float*)d_in[9];
    const float* W2  = (const float*)d_in[10];
    const float* b2  = (const float*)d_in[11];
    const float* We2 = (const float*)d_in[12];
    const float* be2 = (const float*)d_in[13];
    const float* g2  = (const float*)d_in[14];
    const float* bt2 = (const float*)d_in[15];
    const float* A1w = (const float*)d_in[16];
    const float* A1b = (const float*)d_in[17];
    const float* Ag1 = (const float*)d_in[18];
    const float* Ab1 = (const float*)d_in[19];
    const float* A2w = (const float*)d_in[20];
    const float* A2b = (const float*)d_in[21];
    const float* Ag2 = (const float*)d_in[22];
    const float* Ab2 = (const float*)d_in[23];
    const float* A3w = (const float*)d_in[24];
    const float* A3b = (const float*)d_in[25];
    float* out = (float*)d_out;

    float* ws      = (float*)d_ws;
    float* xpa     = ws;                       // [NN*FD]
    float* hpre    = ws + (long)NN * FD;       // [NN*FD]
    float* stats   = ws + 2L * NN * FD;        // 512 + NG*FD floats
    float* colsum1 = stats;
    float* colsq1  = stats + 128;
    float* colsum2 = stats + 256;
    float* colsq2  = stats + 384;
    float* pooled  = stats + 512;
    int*   ibase   = (int*)(stats + 512 + NG * FD);
    int2*  perm    = (int2*)ibase;             // [NE]
    int*   off     = ibase + 2 * NE;           // [NN+2]
    int*   cur     = off + NN + 2;             // [NN]
    int*   chunk   = cur + NN;                 // [256]

    hipMemsetAsync(off, 0, (NN + 2) * sizeof(int), stream);
    hipMemsetAsync(stats, 0, (512 + NG * FD) * sizeof(float), stream);

    // CSR build (once; shared by both stages)
    count_kernel<<<NE / 256, 256, 0, stream>>>(ei, off);
    scan1_kernel<<<NCH, 256, 0, stream>>>(off, chunk);
    scan2_kernel<<<1, 256, 0, stream>>>(chunk);
    scan3_kernel<<<NCH, 256, 0, stream>>>(off, cur, chunk);
    scatter_kernel<<<NE / 256, 256, 0, stream>>>(ei, cur, perm);

    // stage 1
    edge_agg_kernel<false><<<NN / (2 * NPW), 128, 0, stream>>>(
        x, nullptr, nullptr, nullptr, nullptr, ea, off, perm, We1, be1, xpa);
    node_kernel<<<768, 256, 0, stream>>>(xpa, W1, b1, hpre, colsum1, colsq1);

    // stage 2 (BN+relu of stage 1 fused into the gather)
    edge_agg_kernel<true><<<NN / (2 * NPW), 128, 0, stream>>>(
        hpre, colsum1, colsq1, g1, bt1, ea, off, perm, We2, be2, xpa);
    node_kernel<<<768, 256, 0, stream>>>(xpa, W2, b2, hpre, colsum2, colsq2);

    norm_pool_kernel<<<(NN + 127) / 128, 256, 0, stream>>>(
        hpre, colsum2, colsq2, g2, bt2, batch, pooled);
    mlp_kernel<<<1, 256, 0, stream>>>(pooled, batch, A1w, A1b, Ag1, Ab1,
                                      A2w, A2b, Ag2, Ab2, A3w, A3b, out);
}

// Round 7
// 919.518 us; speedup vs baseline: 2.0576x; 1.0879x over previous
//
#include <hip/hip_runtime.h>
#include <math.h>

#define NN 50000
#define NE 800000
#define FD 128
#define EDD 32
#define NG 64
#define NA 16
#define EPSV 1e-5f
#define NCH 196            // ceil(NN/256) chunks for the scan
#define EC 32              // edges staged per chunk per wave
#define NPW 4              // nodes per body
#define BR 128             // node GEMM: rows per block tile
#define BK 32              // node GEMM: k panel

typedef float v2f __attribute__((ext_vector_type(2)));

__device__ __forceinline__ float sigf(float v) { return 1.0f / (1.0f + __expf(-v)); }
__device__ __forceinline__ v2f mk2(float a, float b) { v2f r; r.x = a; r.y = b; return r; }
__device__ __forceinline__ v2f pfma(v2f a, v2f b, v2f c) { return __builtin_elementwise_fma(a, b, c); }
__device__ __forceinline__ v2f pmax0(v2f a) { return __builtin_elementwise_max(a, mk2(0.f, 0.f)); }

// ============ counting sort of edges by dst (CSR build) ====================
__global__ __launch_bounds__(256) void count_kernel(const int* __restrict__ ei,
                                                    int* __restrict__ off)
{
    const int e = blockIdx.x * 256 + threadIdx.x;
    atomicAdd(&off[ei[NE + e]], 1);
}

__global__ __launch_bounds__(256) void scan1_kernel(const int* __restrict__ off,
                                                    int* __restrict__ chunk)
{
    __shared__ int red[256];
    const int i = blockIdx.x * 256 + threadIdx.x;
    red[threadIdx.x] = (i < NN) ? off[i] : 0;
    __syncthreads();
    for (int o = 128; o > 0; o >>= 1) {
        if (threadIdx.x < o) red[threadIdx.x] += red[threadIdx.x + o];
        __syncthreads();
    }
    if (threadIdx.x == 0) chunk[blockIdx.x] = red[0];
}

__global__ __launch_bounds__(256) void scan2_kernel(int* __restrict__ chunk)
{
    __shared__ int sh[256];
    const int t = threadIdx.x;
    const int v = (t < NCH) ? chunk[t] : 0;
    sh[t] = v;
    __syncthreads();
    for (int o = 1; o < 256; o <<= 1) {
        int x = (t >= o) ? sh[t - o] : 0;
        __syncthreads();
        sh[t] += x;
        __syncthreads();
    }
    if (t < NCH) chunk[t] = sh[t] - v;
}

__global__ __launch_bounds__(256) void scan3_kernel(int* __restrict__ off,
                                                    int* __restrict__ cur,
                                                    const int* __restrict__ chunk)
{
    __shared__ int sh[256];
    const int t = threadIdx.x;
    const int i = blockIdx.x * 256 + t;
    const int v = (i < NN) ? off[i] : 0;
    sh[t] = v;
    __syncthreads();
    for (int o = 1; o < 256; o <<= 1) {
        int x = (t >= o) ? sh[t - o] : 0;
        __syncthreads();
        sh[t] += x;
        __syncthreads();
    }
    const int ex = sh[t] - v + chunk[blockIdx.x];
    if (i < NN) { off[i] = ex; cur[i] = ex; }
    if (i == 0) off[NN] = NE;
}

__global__ __launch_bounds__(256) void scatter_kernel(const int* __restrict__ ei,
                                                      int* __restrict__ cur,
                                                      int2* __restrict__ perm)
{
    const int e = blockIdx.x * 256 + threadIdx.x;
    const int src = ei[e];
    const int dst = ei[NE + e];
    const int pos = atomicAdd(&cur[dst], 1);
    perm[pos] = make_int2(src, e);
}

// ============ gather edge stage: persistent waves + work stealing ==========
// Each wave grabs 8-node units off a global counter; weight regs amortized.
template<bool TR>
__global__ __launch_bounds__(128) void edge_agg_kernel(
    const float* __restrict__ xin, const float* __restrict__ cs,
    const float* __restrict__ cq, const float* __restrict__ ga,
    const float* __restrict__ bb, const float* __restrict__ eattr,
    const int* __restrict__ off, const int2* __restrict__ perm,
    const float* __restrict__ We, const float* __restrict__ be,
    int* __restrict__ ctr, float* __restrict__ xpa)
{
    __shared__ float ea_s[2][EC * EDD];   // 8 KB, per-wave private
    __shared__ int   src_s[2][EC];
    const int t = threadIdx.x;
    const int w = t >> 6;
    const int l = t & 63;

    // packed weights: wk[k] = {We[l][k], We[l+64][k]}
    v2f wk[EDD];
    {
        const float4* a  = (const float4*)(We + l * EDD);
        const float4* b2 = (const float4*)(We + (l + 64) * EDD);
#pragma unroll
        for (int i = 0; i < 8; ++i) {
            const float4 va = a[i], vb = b2[i];
            wk[4*i+0] = mk2(va.x, vb.x);
            wk[4*i+1] = mk2(va.y, vb.y);
            wk[4*i+2] = mk2(va.z, vb.z);
            wk[4*i+3] = mk2(va.w, vb.w);
        }
    }
    const v2f bev = mk2(be[l], be[l + 64]);
    v2f Av = mk2(1.f, 1.f), Bv = mk2(0.f, 0.f);
    if (TR) {
        const float invN = 1.0f / (float)NN;
        const float m0 = cs[l] * invN;
        const float i0 = rsqrtf(cq[l] * invN - m0 * m0 + EPSV);
        const float m1 = cs[l + 64] * invN;
        const float i1 = rsqrtf(cq[l + 64] * invN - m1 * m1 + EPSV);
        Av = mk2(i0 * ga[l], i1 * ga[l + 64]);
        Bv = mk2(bb[l] - m0 * Av.x, bb[l + 64] - m1 * Av.y);
    }
    const int p   = l & 7;
    const int jb0 = l >> 3;

    auto ldx = [&](int node) -> v2f {
        v2f v = mk2(xin[(long)node * FD + l], xin[(long)node * FD + 64 + l]);
        return TR ? pmax0(pfma(v, Av, Bv)) : v;
    };

    for (;;) {
        int u = 0;
        if (l == 0) u = atomicAdd(ctr, 1);
        u = __shfl(u, 0);
        if (u >= NN / 8) break;
#pragma unroll 1
        for (int rep = 0; rep < 2; ++rep) {
            const int n0 = u * 8 + rep * NPW;
            const int o0 = off[n0];
            const int o1 = off[n0 + 1];
            const int o2 = off[n0 + 2];
            const int o3 = off[n0 + 3];
            const int o4 = off[n0 + 4];
            const v2f ni0 = ldx(n0), ni1 = ldx(n0 + 1);
            const v2f ni2 = ldx(n0 + 2), ni3 = ldx(n0 + 3);
            const int nchk = (o4 - o0 + EC - 1) / EC;

            float4 pf[4];
            int    psrc = 0;
            auto prefetch = [&](int ch) {
                const int base = o0 + ch * EC;
                const int n = min(EC, o4 - base);
#pragma unroll
                for (int r = 0; r < 4; ++r) {
                    const int jj = jb0 + 8 * r;
                    pf[r] = (jj < n)
                        ? *(const float4*)(eattr + (long)perm[base + jj].y * EDD + p * 4)
                        : make_float4(0.f, 0.f, 0.f, 0.f);
                }
                if (l < EC && l < n) psrc = perm[base + l].x;
            };

            int cur = n0;
            int nxt_end = o1;
            v2f acc = ni0;
            int eidx = o0;

            if (nchk > 0) prefetch(0);
            for (int ch = 0; ch < nchk; ++ch) {
#pragma unroll
                for (int r = 0; r < 4; ++r)
                    *(float4*)(&ea_s[w][(jb0 + 8 * r) * EDD + p * 4]) = pf[r];
                if (l < EC) src_s[w][l] = psrc;
                const int base = o0 + ch * EC;
                const int n = min(EC, o4 - base);
                if (ch + 1 < nchk) prefetch(ch + 1);

                v2f cx[4];
#pragma unroll
                for (int q = 0; q < 4; ++q) {
                    if (q < n) {
                        const int s = src_s[w][q];
                        cx[q] = mk2(xin[(long)s * FD + l], xin[(long)s * FD + 64 + l]);
                    } else cx[q] = mk2(0.f, 0.f);
                }
                const int ng = (n + 3) >> 2;
                for (int g = 0; g < ng; ++g) {
                    const int jg = g * 4;
                    v2f nx[4];
#pragma unroll
                    for (int q = 0; q < 4; ++q) {
                        const int j = jg + 4 + q;
                        if (j < n) {
                            const int s = src_s[w][j];
                            nx[q] = mk2(xin[(long)s * FD + l], xin[(long)s * FD + 64 + l]);
                        } else nx[q] = mk2(0.f, 0.f);
                    }
#pragma unroll
                    for (int q = 0; q < 4; ++q) {
                        const int j = jg + q;
                        if (j < n) {
                            while (eidx == nxt_end) {
                                xpa[(long)cur * FD + l]      = acc.x;
                                xpa[(long)cur * FD + 64 + l] = acc.y;
                                ++cur;
                                acc     = (cur == n0 + 1) ? ni1 : (cur == n0 + 2) ? ni2 : ni3;
                                nxt_end = (cur == n0 + 1) ? o2  : (cur == n0 + 2) ? o3  : o4;
                            }
                            const float4* ev = (const float4*)(&ea_s[w][j * EDD]);
                            v2f ma = bev, mb = mk2(0.f, 0.f);
#pragma unroll
                            for (int k = 0; k < 8; ++k) {
                                const float4 v = ev[k];
                                ma = pfma(mk2(v.x, v.x), wk[4*k+0], ma);
                                mb = pfma(mk2(v.y, v.y), wk[4*k+1], mb);
                                ma = pfma(mk2(v.z, v.z), wk[4*k+2], ma);
                                mb = pfma(mk2(v.w, v.w), wk[4*k+3], mb);
                            }
                            const v2f tx = TR ? pmax0(pfma(cx[q], Av, Bv)) : cx[q];
                            acc += pmax0(ma + mb + tx);
                            ++eidx;
                        }
                    }
#pragma unroll
                    for (int q = 0; q < 4; ++q) cx[q] = nx[q];
                }
            }
            for (;;) {
                xpa[(long)cur * FD + l]      = acc.x;
                xpa[(long)cur * FD + 64 + l] = acc.y;
                if (cur == n0 + 3) break;
                ++cur;
                acc = (cur == n0 + 1) ? ni1 : (cur == n0 + 2) ? ni2 : ni3;
            }
        }
    }
}

// ============ node GEMM: hpre = xpa @ W^T + b, fused BN column stats =======
// Register-blocked outer product: 128x128 block tile, 8x8 per thread,
// A and W k-panels staged transposed in LDS ([k][r], [k][c]).
__global__ __launch_bounds__(256) void node_kernel(
    const float* __restrict__ xpa, const float* __restrict__ W,
    const float* __restrict__ b, float* __restrict__ hpre,
    float* __restrict__ colsum, float* __restrict__ colsq)
{
    __shared__ float As[BK][BR + 4];
    __shared__ float Ws[BK][128 + 4];
    const int t = threadIdx.x;
    const int cg = t & 15;        // col group -> cols c0..c0+7
    const int rg = t >> 4;        // row group -> rows rg*8..+7
    const int c0 = cg * 8;
    const int r0 = blockIdx.x * BR;
    const int sr = t >> 1;        // staging row/col 0..127
    const int kq = (t & 1) * 16;  // staging k offset

    float acc[8][8];
#pragma unroll
    for (int j = 0; j < 8; ++j)
#pragma unroll
        for (int i = 0; i < 8; ++i) acc[j][i] = 0.f;

#pragma unroll 1
    for (int pn = 0; pn < 4; ++pn) {
        const int k0 = pn * BK;
        __syncthreads();
        {
            const int rG = r0 + sr;
            const float* ap = xpa + (long)rG * FD + k0 + kq;
#pragma unroll
            for (int i = 0; i < 4; ++i) {
                const float4 v = (rG < NN) ? *(const float4*)(ap + i * 4)
                                           : make_float4(0.f, 0.f, 0.f, 0.f);
                As[kq + i * 4 + 0][sr] = v.x;
                As[kq + i * 4 + 1][sr] = v.y;
                As[kq + i * 4 + 2][sr] = v.z;
                As[kq + i * 4 + 3][sr] = v.w;
            }
        }
        {
            const float* wp2 = W + sr * FD + k0 + kq;
#pragma unroll
            for (int i = 0; i < 4; ++i) {
                const float4 v = *(const float4*)(wp2 + i * 4);
                Ws[kq + i * 4 + 0][sr] = v.x;
                Ws[kq + i * 4 + 1][sr] = v.y;
                Ws[kq + i * 4 + 2][sr] = v.z;
                Ws[kq + i * 4 + 3][sr] = v.w;
            }
        }
        __syncthreads();
#pragma unroll
        for (int k = 0; k < BK; ++k) {
            const float4 a0 = *(const float4*)&As[k][rg * 8];
            const float4 a1 = *(const float4*)&As[k][rg * 8 + 4];
            const float4 w0 = *(const float4*)&Ws[k][c0];
            const float4 w1 = *(const float4*)&Ws[k][c0 + 4];
            const float av[8] = {a0.x,a0.y,a0.z,a0.w,a1.x,a1.y,a1.z,a1.w};
            const float wv[8] = {w0.x,w0.y,w0.z,w0.w,w1.x,w1.y,w1.z,w1.w};
#pragma unroll
            for (int j = 0; j < 8; ++j)
#pragma unroll
                for (int i = 0; i < 8; ++i)
                    acc[j][i] = fmaf(av[j], wv[i], acc[j][i]);
        }
    }
    float bv[8];
#pragma unroll
    for (int i = 0; i < 8; ++i) bv[i] = b[c0 + i];
    float s1[8], s2[8];
#pragma unroll
    for (int i = 0; i < 8; ++i) { s1[i] = 0.f; s2[i] = 0.f; }
#pragma unroll
    for (int j = 0; j < 8; ++j) {
        const int r = r0 + rg * 8 + j;
        if (r < NN) {
            float v[8];
#pragma unroll
            for (int i = 0; i < 8; ++i) {
                v[i] = acc[j][i] + bv[i];
                s1[i] += v[i];
                s2[i] += v[i] * v[i];
            }
            *(float4*)(hpre + (long)r * FD + c0)     = make_float4(v[0],v[1],v[2],v[3]);
            *(float4*)(hpre + (long)r * FD + c0 + 4) = make_float4(v[4],v[5],v[6],v[7]);
        }
    }
    __syncthreads();
#pragma unroll
    for (int i = 0; i < 8; ++i) As[rg][c0 + i] = s1[i];
    __syncthreads();
    if (t < 128) {
        float s = 0.f;
#pragma unroll
        for (int g = 0; g < 16; ++g) s += As[g][t];
        atomicAdd(&colsum[t], s);
    }
    __syncthreads();
#pragma unroll
    for (int i = 0; i < 8; ++i) As[rg][c0 + i] = s2[i];
    __syncthreads();
    if (t < 128) {
        float s = 0.f;
#pragma unroll
        for (int g = 0; g < 16; ++g) s += As[g][t];
        atomicAdd(&colsq[t], s);
    }
}

// ============ BN + relu + sigmoid + per-graph pooled sums (layer 2) ========
__global__ __launch_bounds__(256) void norm_pool_kernel(
    const float* __restrict__ hpre, const float* __restrict__ cs,
    const float* __restrict__ cq, const float* __restrict__ ga,
    const float* __restrict__ bb, const int* __restrict__ batch,
    float* __restrict__ pooled)
{
    __shared__ float pl[NG * FD];
    const int t = threadIdx.x;
    const int c = t & 127;
    const int half = t >> 7;
    const int r0 = blockIdx.x * 128;
    const int rend = min(r0 + 128, NN);
    const int gmin = batch[r0];
    const int gmax = batch[rend - 1];
    const int span = gmax - gmin + 1;
    for (int i = t; i < span * FD; i += 256) pl[i] = 0.f;
    __syncthreads();
    const float invN = 1.0f / (float)NN;
    const float m = cs[c] * invN;
    const float iv = rsqrtf(cq[c] * invN - m * m + EPSV);
    const float gg = ga[c];
    const float bt = bb[c];
    for (int ir = half; ir < 128; ir += 2) {
        const int r = r0 + ir;
        if (r >= rend) break;
        float v = (hpre[(long)r * FD + c] - m) * iv * gg + bt;
        v = sigf(fmaxf(v, 0.f));
        atomicAdd(&pl[(batch[r] - gmin) * FD + c], v);
    }
    __syncthreads();
    for (int i = t; i < span * FD; i += 256) atomicAdd(&pooled[gmin * FD + i], pl[i]);
}

__device__ __forceinline__ int lbound(const int* __restrict__ a, int n, int v)
{
    int lo = 0, hi = n;
    while (lo < hi) { const int mid = (lo + hi) >> 1; if (a[mid] < v) lo = mid + 1; else hi = mid; }
    return lo;
}

// ============ action MLP head, single block ================================
__global__ __launch_bounds__(256) void mlp_kernel(
    const float* __restrict__ pooled, const int* __restrict__ batch,
    const float* __restrict__ A1w, const float* __restrict__ A1b,
    const float* __restrict__ Ag1, const float* __restrict__ Ab1,
    const float* __restrict__ A2w, const float* __restrict__ A2b,
    const float* __restrict__ Ag2, const float* __restrict__ Ab2,
    const float* __restrict__ A3w, const float* __restrict__ A3b,
    float* __restrict__ out)
{
    __shared__ float Z[NG * FD];
    __shared__ float red[256];
    __shared__ float ml[128], il[128];
    __shared__ float cr[NG];
    const int t = threadIdx.x;
    const int c = t & 127;
    const int half = t >> 7;
    if (t < NG) {
        const int lo = lbound(batch, NN, t);
        const int hi = lbound(batch, NN, t + 1);
        cr[t] = 1.0f / fmaxf((float)(hi - lo), 1.0f);
    }
    float acc[32];
#pragma unroll
    for (int ii = 0; ii < 32; ++ii) acc[ii] = 0.f;
#pragma unroll 1
    for (int kc = 0; kc < 4; ++kc) {
        float4 wr[8];
        const float4* wp = (const float4*)(A1w + c * FD + kc * 32);
#pragma unroll
        for (int i = 0; i < 8; ++i) wr[i] = wp[i];
#pragma unroll
        for (int ii = 0; ii < 32; ++ii) {
            const int gi = half + 2 * ii;
            const float4* pp = (const float4*)(pooled + gi * FD + kc * 32);
            float d = 0.f;
#pragma unroll
            for (int i = 0; i < 8; ++i) {
                const float4 w4 = wr[i], p4 = pp[i];
                d += w4.x * p4.x + w4.y * p4.y + w4.z * p4.z + w4.w * p4.w;
            }
            acc[ii] += d;
        }
    }
    __syncthreads();
    float s1 = 0.f, s2 = 0.f;
    {
        const float bc = A1b[c];
#pragma unroll
        for (int ii = 0; ii < 32; ++ii) {
            const int gi = half + 2 * ii;
            const float a = fmaf(acc[ii], cr[gi], bc);
            acc[ii] = a; s1 += a; s2 += a * a;
        }
    }
    red[t] = s1; __syncthreads();
    if (t < 128) ml[c] = (red[t] + red[t + 128]) * (1.0f / NG);
    __syncthreads();
    red[t] = s2; __syncthreads();
    if (t < 128) {
        const float ms = (red[t] + red[t + 128]) * (1.0f / NG);
        const float mm = ml[c];
        il[c] = rsqrtf(ms - mm * mm + EPSV);
    }
    __syncthreads();
    {
        const float mm = ml[c], iv = il[c], gg = Ag1[c], bb = Ab1[c];
#pragma unroll
        for (int ii = 0; ii < 32; ++ii) {
            const int gi = half + 2 * ii;
            Z[gi * FD + c] = fmaxf((acc[ii] - mm) * iv * gg + bb, 0.f);
        }
    }
    __syncthreads();
#pragma unroll
    for (int ii = 0; ii < 32; ++ii) acc[ii] = 0.f;
#pragma unroll 1
    for (int kc = 0; kc < 4; ++kc) {
        float4 wr[8];
        const float4* wp = (const float4*)(A2w + c * FD + kc * 32);
#pragma unroll
        for (int i = 0; i < 8; ++i) wr[i] = wp[i];
#pragma unroll
        for (int ii = 0; ii < 32; ++ii) {
            const int gi = half + 2 * ii;
            const float4* pp = (const float4*)(&Z[gi * FD + kc * 32]);
            float d = 0.f;
#pragma unroll
            for (int i = 0; i < 8; ++i) {
                const float4 w4 = wr[i], p4 = pp[i];
                d += w4.x * p4.x + w4.y * p4.y + w4.z * p4.z + w4.w * p4.w;
            }
            acc[ii] += d;
        }
    }
    s1 = 0.f; s2 = 0.f;
    {
        const float bc = A2b[c];
#pragma unroll
        for (int ii = 0; ii < 32; ++ii) {
            const float a = acc[ii] + bc;
            acc[ii] = a; s1 += a; s2 += a * a;
        }
    }
    red[t] = s1; __syncthreads();
    if (t < 128) ml[c] = (red[t] + red[t + 128]) * (1.0f / NG);
    __syncthreads();
    red[t] = s2; __syncthreads();
    if (t < 128) {
        const float ms = (red[t] + red[t + 128]) * (1.0f / NG);
        const float mm = ml[c];
        il[c] = rsqrtf(ms - mm * mm + EPSV);
    }
    __syncthreads();
    {
        const float mm = ml[c], iv = il[c], gg = Ag2[c], bb = Ab2[c];
#pragma unroll
        for (int ii = 0; ii < 32; ++ii) {
            const int gi = half + 2 * ii;
            Z[gi * FD + c] = fmaxf((acc[ii] - mm) * iv * gg + bb, 0.f);
        }
    }
    __syncthreads();
    for (int i = t; i < NG * NA; i += 256) {
        const int gi = i >> 4;
        const int a = i & 15;
        const float4* wp = (const float4*)(A3w + a * FD);
        const float4* pp = (const float4*)(&Z[gi * FD]);
        float d = A3b[a];
#pragma unroll 8
        for (int k4 = 0; k4 < 32; ++k4) {
            const float4 w4 = wp[k4];
            const float4 p4 = pp[k4];
            d += w4.x * p4.x + w4.y * p4.y + w4.z * p4.z + w4.w * p4.w;
        }
        out[i] = sigf(d);
    }
}

extern "C" void kernel_launch(void* const* d_in, const int* in_sizes, int n_in,
                              void* d_out, int out_size, void* d_ws, size_t ws_size,
                              hipStream_t stream)
{
    const float* x     = (const float*)d_in[0];
    const float* ea    = (const float*)d_in[1];
    const int*   ei    = (const int*)d_in[2];
    const int*   batch = (const int*)d_in[3];
    const float* W1  = (const float*)d_in[4];
    const float* b1  = (const float*)d_in[5];
    const float* We1 = (const float*)d_in[6];
    const float* be1 = (const float*)d_in[7];
    const float* g1  = (const float*)d_in[8];
    const float* bt1 = (const float*)d_in[9];
    const float* W2  = (const float*)d_in[10];
    const float* b2  = (const float*)d_in[11];
    const float* We2 = (const float*)d_in[12];
    const float* be2 = (const float*)d_in[13];
    const float* g2  = (const float*)d_in[14];
    const float* bt2 = (const float*)d_in[15];
    const float* A1w = (const float*)d_in[16];
    const float* A1b = (const float*)d_in[17];
    const float* Ag1 = (const float*)d_in[18];
    const float* Ab1 = (const float*)d_in[19];
    const float* A2w = (const float*)d_in[20];
    const float* A2b = (const float*)d_in[21];
    const float* Ag2 = (const float*)d_in[22];
    const float* Ab2 = (const float*)d_in[23];
    const float* A3w = (const float*)d_in[24];
    const float* A3b = (const float*)d_in[25];
    float* out = (float*)d_out;

    float* ws      = (float*)d_ws;
    float* xpa     = ws;                       // [NN*FD]
    float* hpre    = ws + (long)NN * FD;       // [NN*FD]
    float* stats   = ws + 2L * NN * FD;        // 512 + NG*FD + 8 floats
    float* colsum1 = stats;
    float* colsq1  = stats + 128;
    float* colsum2 = stats + 256;
    float* colsq2  = stats + 384;
    float* pooled  = stats + 512;
    int*   ctr1    = (int*)(stats + 512 + NG * FD);
    int*   ctr2    = ctr1 + 1;
    int*   ibase   = (int*)(stats + 512 + NG * FD + 8);
    int2*  perm    = (int2*)ibase;             // [NE]
    int*   off     = ibase + 2 * NE;           // [NN+2]
    int*   cur     = off + NN + 2;             // [NN]
    int*   chunk   = cur + NN;                 // [256]

    hipMemsetAsync(off, 0, (NN + 2) * sizeof(int), stream);
    hipMemsetAsync(stats, 0, (512 + NG * FD + 8) * sizeof(float), stream);

    // CSR build (once; shared by both stages)
    count_kernel<<<NE / 256, 256, 0, stream>>>(ei, off);
    scan1_kernel<<<NCH, 256, 0, stream>>>(off, chunk);
    scan2_kernel<<<1, 256, 0, stream>>>(chunk);
    scan3_kernel<<<NCH, 256, 0, stream>>>(off, cur, chunk);
    scatter_kernel<<<NE / 256, 256, 0, stream>>>(ei, cur, perm);

    // stage 1
    edge_agg_kernel<false><<<2048, 128, 0, stream>>>(
        x, nullptr, nullptr, nullptr, nullptr, ea, off, perm, We1, be1, ctr1, xpa);
    node_kernel<<<(NN + BR - 1) / BR, 256, 0, stream>>>(xpa, W1, b1, hpre, colsum1, colsq1);

    // stage 2 (BN+relu of stage 1 fused into the gather)
    edge_agg_kernel<true><<<2048, 128, 0, stream>>>(
        hpre, colsum1, colsq1, g1, bt1, ea, off, perm, We2, be2, ctr2, xpa);
    node_kernel<<<(NN + BR - 1) / BR, 256, 0, stream>>>(xpa, W2, b2, hpre, colsum2, colsq2);

    norm_pool_kernel<<<(NN + 127) / 128, 256, 0, stream>>>(
        hpre, colsum2, colsq2, g2, bt2, batch, pooled);
    mlp_kernel<<<1, 256, 0, stream>>>(pooled, batch, A1w, A1b, Ag1, Ab1,
                                      A2w, A2b, Ag2, Ab2, A3w, A3b, out);
}